// Round 6
// baseline (446.893 us; speedup 1.0000x reference)
//
#include <hip/hip_runtime.h>
#include <hip/hip_bf16.h>
#include <math.h>

// ---------------------------------------------------------------------------
// Problem constants
// ---------------------------------------------------------------------------
#define NM 100000
#define ND 20000
#define NA 50000
#define EDG 300000
#define CAP 32   // max in-degree slots per movie node (Poisson(6): P(>32)~1.6e-14)

typedef __attribute__((ext_vector_type(8))) short shortx8;
typedef __attribute__((ext_vector_type(4))) float floatx4;
typedef __attribute__((ext_vector_type(4))) int intx4;

__device__ __forceinline__ float bf2f(unsigned int u) {
    return __uint_as_float(u << 16);
}
__device__ __forceinline__ unsigned short f2bf(float f) {   // RNE (precomp only)
    unsigned int x = __float_as_uint(f);
    unsigned int r = x + 0x7fffu + ((x >> 16) & 1u);
    return (unsigned short)(r >> 16);
}
__device__ __forceinline__ unsigned short f2bf_fast(float f) {  // round-half-up
    return (unsigned short)((__float_as_uint(f) + 0x8000u) >> 16);
}
// pack 2 f32 -> dword [bf16(a) | bf16(b)<<16] : 2 add + 1 v_perm
__device__ __forceinline__ unsigned int pkbf2(float a, float b) {
    return __builtin_amdgcn_perm(__float_as_uint(b) + 0x8000u,
                                 __float_as_uint(a) + 0x8000u,
                                 0x07060302u);
}
__device__ __forceinline__ float gelu_exact(float x) {
    return 0.5f * x * (1.0f + erff(x * 0.70710678118654752f));
}

// ---------------------------------------------------------------------------
// Workspace layout (bytes) — total ~78.4 MB
// ---------------------------------------------------------------------------
static const size_t OFF_BT_Q      = 0;          // 144x256 bf16 (Wq^T composed | skip cols | zero)
static const size_t OFF_BT_KAMV_D = 73728;      // 256x128 bf16 (rows 0-127 ka, 128-255 mv)
static const size_t OFF_BT_KAMV_A = 139264;     // 256x128 bf16
static const size_t OFF_WKA_D     = 204800;     // 128x128 f32
static const size_t OFF_WVM_D     = 270336;     // 128x128 f32
static const size_t OFF_WKA_A     = 335872;     // 128x128 f32
static const size_t OFF_WVM_A     = 401408;     // 128x128 f32
static const size_t OFF_BQ        = 466944;     // 144 f32
static const size_t OFF_B_KAMV_D  = 467520;     // 256 f32
static const size_t OFF_B_KAMV_A  = 468544;     // 256 f32
static const size_t OFF_BKA_D     = 469568;     // 128 f32
static const size_t OFF_BVM_D     = 470080;     // 128 f32
static const size_t OFF_BKA_A     = 470592;     // 128 f32
static const size_t OFF_BVM_A     = 471104;     // 128 f32
static const size_t OFF_WALS      = 471616;     // 128x8 f32 (g·Wa[0]@Wlin)
static const size_t OFF_BFIN      = 475712;     // 8 f32
static const size_t OFF_Q0        = 524288;     // NM*128 bf16   (25.6 MB)
static const size_t OFF_SKIPB     = 26124288;   // NM*8 f32      (3.2 MB)
static const size_t OFF_KAMV_D    = 29324288;   // ND*256 bf16   (10.24 MB)
static const size_t OFF_KAMV_A    = 39564288;   // NA*256 bf16   (25.6 MB)
static const size_t OFF_COUNTS    = 65164288;   // NM int32
static const size_t OFF_SLOTS     = 65564288;   // NM*CAP int32  (12.8 MB)
#define KAMV_A_DELTA 10240000   // OFF_KAMV_A - OFF_KAMV_D

// ---------------------------------------------------------------------------
// K0a: fold a_rel/m_rel/p·scale into Wk/Wv; epilogue tables; zero counts
// ---------------------------------------------------------------------------
__global__ __launch_bounds__(256) void precompA(
    const float* __restrict__ Wk, const float* __restrict__ bk,
    const float* __restrict__ Wv, const float* __restrict__ bv,
    const float* __restrict__ Wa, const float* __restrict__ ba,
    const float* __restrict__ Wlin, const float* __restrict__ blin,
    const float* __restrict__ a_rel, const float* __restrict__ m_rel,
    const float* __restrict__ p_rel, const float* __restrict__ skip,
    const float* __restrict__ bpre,
    char* __restrict__ ws)
{
    int tid = blockIdx.x * 256 + threadIdx.x;
    if (tid < 65536) {
        int mat = tid >> 14, rem = tid & 16383;
        int e = rem >> 7, hf = rem & 127, h = hf >> 4, f = hf & 15;
        const float* Wsrc; const float* R; float sc; float* dst;
        if (mat == 0)      { Wsrc = Wk + 16384; R = a_rel;        sc = p_rel[h]     * 0.25f; dst = (float*)(ws + OFF_WKA_D); }
        else if (mat == 1) { Wsrc = Wv + 16384; R = m_rel;        sc = 1.0f;                 dst = (float*)(ws + OFF_WVM_D); }
        else if (mat == 2) { Wsrc = Wk + 32768; R = a_rel + 2048; sc = p_rel[8 + h] * 0.25f; dst = (float*)(ws + OFF_WKA_A); }
        else               { Wsrc = Wv + 32768; R = m_rel + 2048; sc = 1.0f;                 dst = (float*)(ws + OFF_WVM_A); }
        float s = 0.0f;
        for (int d = 0; d < 16; d++)
            s += Wsrc[e * 128 + h * 16 + d] * R[h * 256 + d * 16 + f];
        dst[e * 128 + hf] = s * sc;
    } else if (tid < 66048) {
        int idx = tid - 65536;
        int mat = idx >> 7, hf = idx & 127, h = hf >> 4, f = hf & 15;
        const float* bsrc; const float* R; float sc; float* dst;
        if (mat == 0)      { bsrc = bk + 128; R = a_rel;        sc = p_rel[h]     * 0.25f; dst = (float*)(ws + OFF_BKA_D); }
        else if (mat == 1) { bsrc = bv + 128; R = m_rel;        sc = 1.0f;                 dst = (float*)(ws + OFF_BVM_D); }
        else if (mat == 2) { bsrc = bk + 256; R = a_rel + 2048; sc = p_rel[8 + h] * 0.25f; dst = (float*)(ws + OFF_BKA_A); }
        else               { bsrc = bv + 256; R = m_rel + 2048; sc = 1.0f;                 dst = (float*)(ws + OFF_BVM_A); }
        float s = 0.0f;
        for (int d = 0; d < 16; d++)
            s += bsrc[h * 16 + d] * R[h * 256 + d * 16 + f];
        dst[hf] = s * sc;
    } else if (tid < 67072) {
        // WaLs[j][c] = g * sum_o Wa[0][j][o] * Wlin[o][c]
        int idx = tid - 66048;
        int j = idx >> 3, c = idx & 7;
        float g = 1.0f / (1.0f + __expf(-skip[0]));
        float s = 0.0f;
        for (int o = 0; o < 128; o++)
            s += Wa[j * 128 + o] * Wlin[o * 8 + c];
        ((float*)(ws + OFF_WALS))[j * 8 + c] = g * s;
    } else if (tid < 67080) {
        int c = tid - 67072;
        float g = 1.0f / (1.0f + __expf(-skip[0]));
        float s1 = 0.0f, s2 = 0.0f;
        for (int o = 0; o < 128; o++) {
            s1 += ba[o]   * Wlin[o * 8 + c];
            s2 += bpre[o] * Wlin[o * 8 + c];
        }
        ((float*)(ws + OFF_BFIN))[c] = g * s1 + (1.0f - g) * s2 + blin[c];
    } else if (tid < 67080 + NM) {
        ((int*)(ws + OFF_COUNTS))[tid - 67080] = 0;   // zero edge counters
    }
}

// ---------------------------------------------------------------------------
// K0b: compose pre-encoder into projection weights (consumes K0a outputs)
// ---------------------------------------------------------------------------
__global__ __launch_bounds__(256) void precompB(
    const float* __restrict__ Wpre_m, const float* __restrict__ Wpre_d,
    const float* __restrict__ Wpre_a, const float* __restrict__ bpre,
    const float* __restrict__ Wq, const float* __restrict__ bq,
    const float* __restrict__ Wlin, const float* __restrict__ skip,
    char* __restrict__ ws)
{
    int tid = blockIdx.x * 256 + threadIdx.x;
    const float* WKA_D = (const float*)(ws + OFF_WKA_D);
    const float* WVM_D = (const float*)(ws + OFF_WVM_D);
    const float* WKA_A = (const float*)(ws + OFF_WKA_A);
    const float* WVM_A = (const float*)(ws + OFF_WVM_A);

    if (tid < 36864) {
        int n = tid >> 8, c = tid & 255;
        float s = 0.0f;
        if (n < 128) {
            for (int e = 0; e < 128; e++)
                s += Wpre_m[c * 128 + e] * Wq[e * 128 + n];
        } else if (n < 136) {
            int cc = n - 128;
            float g = 1.0f / (1.0f + __expf(-skip[0]));
            for (int e = 0; e < 128; e++)
                s += Wpre_m[c * 128 + e] * Wlin[e * 8 + cc];
            s *= (1.0f - g);
        }
        ((unsigned short*)(ws + OFF_BT_Q))[n * 256 + c] = f2bf(s);
    } else if (tid < 69632) {
        int idx = tid - 36864;
        int nrow = idx >> 7, c = idx & 127;
        const float* Wf = (nrow < 128) ? WKA_D : WVM_D;
        int nc = nrow & 127;
        float s = 0.0f;
        for (int e = 0; e < 128; e++)
            s += Wpre_d[c * 128 + e] * Wf[e * 128 + nc];
        ((unsigned short*)(ws + OFF_BT_KAMV_D))[nrow * 128 + c] = f2bf(s);
    } else if (tid < 102400) {
        int idx = tid - 69632;
        int nrow = idx >> 7, c = idx & 127;
        const float* Wf = (nrow < 128) ? WKA_A : WVM_A;
        int nc = nrow & 127;
        float s = 0.0f;
        for (int e = 0; e < 128; e++)
            s += Wpre_a[c * 128 + e] * Wf[e * 128 + nc];
        ((unsigned short*)(ws + OFF_BT_KAMV_A))[nrow * 128 + c] = f2bf(s);
    } else if (tid < 102544) {
        int n = tid - 102400;
        float s = 0.0f;
        if (n < 128) {
            for (int e = 0; e < 128; e++)
                s += bpre[e] * Wq[e * 128 + n];
            s += bq[n];
        }
        ((float*)(ws + OFF_BQ))[n] = s;
    } else if (tid < 102800) {
        int nrow = tid - 102544;
        const float* Wf  = (nrow < 128) ? WKA_D : WVM_D;
        const float* bf_ = (nrow < 128) ? (const float*)(ws + OFF_BKA_D) : (const float*)(ws + OFF_BVM_D);
        int nc = nrow & 127;
        float s = 0.0f;
        for (int e = 0; e < 128; e++)
            s += bpre[128 + e] * Wf[e * 128 + nc];
        ((float*)(ws + OFF_B_KAMV_D))[nrow] = s + bf_[nc];
    } else if (tid < 103056) {
        int nrow = tid - 102800;
        const float* Wf  = (nrow < 128) ? WKA_A : WVM_A;
        const float* bf_ = (nrow < 128) ? (const float*)(ws + OFF_BKA_A) : (const float*)(ws + OFF_BVM_A);
        int nc = nrow & 127;
        float s = 0.0f;
        for (int e = 0; e < 128; e++)
            s += bpre[256 + e] * Wf[e * 128 + nc];
        ((float*)(ws + OFF_B_KAMV_A))[nrow] = s + bf_[nc];
    }
}

// ---------------------------------------------------------------------------
// Edge scatter: slot = byte offset of source row relative to kamv_d base
// ---------------------------------------------------------------------------
__global__ __launch_bounds__(256) void edge_scatter(
    const int* __restrict__ src_dm, const int* __restrict__ dst_dm,
    const int* __restrict__ src_am, const int* __restrict__ dst_am,
    int* __restrict__ counts, int* __restrict__ slots)
{
    int t = blockIdx.x * 256 + threadIdx.x;
    if (t >= 2 * EDG) return;
    int src, dst, delta;
    if (t < EDG) { src = src_dm[t];       dst = dst_dm[t];       delta = 0; }
    else         { src = src_am[t - EDG]; dst = dst_am[t - EDG]; delta = KAMV_A_DELTA; }
    int pos = atomicAdd(&counts[dst], 1);
    if (pos < CAP) slots[(size_t)dst * CAP + pos] = src * 512 + delta;
}

// ---------------------------------------------------------------------------
// GEMM with LDS-staged A (coalesced f32 loads -> bf16 pack -> LDS) and
// LDS-staged B. K=256 in 2 halves. NT=9 variant emits f32 skip partials.
// K-loop is pure LDS+MFMA: no global access -> no exposed HBM latency.
// ---------------------------------------------------------------------------
#define MFMA16(a, b, c) __builtin_amdgcn_mfma_f32_16x16x32_bf16(a, b, c, 0, 0, 0)

template<int NT, bool SKIP>
__global__ __launch_bounds__(256, 2) void gemm_m(
    const float* __restrict__ A, int M,
    const unsigned short* __restrict__ BT,
    const float* __restrict__ bias,
    unsigned short* __restrict__ outb, int ldout,
    float* __restrict__ skipb)
{
    __shared__ unsigned short a_lds[128 * 136];       // 34.8 KB
    __shared__ unsigned short b_lds[NT * 16 * 136];   // 39.2 KB @ NT=9
    int tid = threadIdx.x;
    int w = tid >> 6, lane = tid & 63;
    int quad = lane >> 4, low = lane & 15;
    int rbase = blockIdx.x * 128 + w * 32;

    floatx4 acc[2][NT] = {};

    for (int hfi = 0; hfi < 2; hfi++) {
        if (hfi) __syncthreads();
        // stage B half: NT*16 rows x 128 k (L2-resident)
        for (int idx = tid; idx < NT * 16 * 16; idx += 256) {
            int n = idx >> 4, ch = idx & 15;
            *(intx4*)(&b_lds[n * 136 + ch * 8]) =
                *(const intx4*)(&BT[(size_t)n * 256 + hfi * 128 + ch * 8]);
        }
        // stage A half: 128 rows x 128 f32, coalesced float4 streams,
        // 16 independent loads/thread -> deep MLP; pack bf16 via v_perm
        for (int f = tid; f < 4096; f += 256) {
            int r = f >> 5, c4 = f & 31;
            int rg = blockIdx.x * 128 + r;
            if (rg >= M) rg = M - 1;
            floatx4 v = *(const floatx4*)(A + (size_t)rg * 256 + hfi * 128 + c4 * 4);
            unsigned long long d =
                ((unsigned long long)pkbf2(v[2], v[3]) << 32) | pkbf2(v[0], v[1]);
            *(unsigned long long*)(&a_lds[r * 136 + c4 * 4]) = d;
        }
        __syncthreads();

        #pragma unroll
        for (int ks = 0; ks < 4; ks++) {
            int ko = ks * 32 + quad * 8;
            shortx8 a0 = *(const shortx8*)(&a_lds[(w * 32 + low) * 136 + ko]);
            shortx8 a1 = *(const shortx8*)(&a_lds[(w * 32 + 16 + low) * 136 + ko]);
            #pragma unroll
            for (int nt = 0; nt < NT; nt++) {
                shortx8 b = *(const shortx8*)(&b_lds[(nt * 16 + low) * 136 + ko]);
                acc[0][nt] = MFMA16(a0, b, acc[0][nt]);
                acc[1][nt] = MFMA16(a1, b, acc[1][nt]);
            }
        }
    }

    #pragma unroll
    for (int mt = 0; mt < 2; mt++) {
        #pragma unroll
        for (int nt = 0; nt < NT; nt++) {
            #pragma unroll
            for (int r = 0; r < 4; r++) {
                int row = rbase + mt * 16 + quad * 4 + r;
                if (row >= M) continue;
                int col = nt * 16 + low;
                float v = acc[mt][nt][r] + bias[col];
                if (SKIP && nt == 8) {
                    if (low < 8) skipb[(size_t)row * 8 + low] = v;
                } else {
                    outb[(size_t)row * ldout + col] = f2bf_fast(v);
                }
            }
        }
    }
}

// ---------------------------------------------------------------------------
// kamv GEMM, LDS-staged A, K=128 (single stage). blockIdx.y selects the
// 128-col panel (ka / mv); blockIdx.x splits director [0,157) / actor rest.
// ---------------------------------------------------------------------------
__global__ __launch_bounds__(256, 2) void gemm_kamv(
    const float* __restrict__ A_d, const float* __restrict__ A_a,
    const unsigned short* __restrict__ BT_d, const unsigned short* __restrict__ BT_a,
    const float* __restrict__ bias_d, const float* __restrict__ bias_a,
    unsigned short* __restrict__ out_d, unsigned short* __restrict__ out_a)
{
    __shared__ unsigned short a_lds[128 * 136];   // 34.8 KB
    __shared__ unsigned short b_lds[128 * 136];   // 34.8 KB
    const int NBLK_D = (ND + 127) / 128;          // 157
    bool isD = (int)blockIdx.x < NBLK_D;
    const float* A           = isD ? A_d    : A_a;
    const unsigned short* BT = (isD ? BT_d : BT_a) + (size_t)blockIdx.y * 128 * 128;
    const float* bias        = (isD ? bias_d : bias_a) + blockIdx.y * 128;
    unsigned short* outb     = isD ? out_d  : out_a;
    int M  = isD ? ND : NA;
    int bx = isD ? (int)blockIdx.x : (int)blockIdx.x - NBLK_D;
    int col_off = blockIdx.y * 128;

    int tid = threadIdx.x;
    int w = tid >> 6, lane = tid & 63;
    int quad = lane >> 4, low = lane & 15;
    int rbase = bx * 128 + w * 32;

    // stage B: 128 rows x 128 k
    for (int idx = tid; idx < 2048; idx += 256) {
        int n = idx >> 4, ch = idx & 15;
        *(intx4*)(&b_lds[n * 136 + ch * 8]) =
            *(const intx4*)(&BT[(size_t)n * 128 + ch * 8]);
    }
    // stage A: 128 rows x 128 f32 coalesced
    for (int f = tid; f < 4096; f += 256) {
        int r = f >> 5, c4 = f & 31;
        int rg = bx * 128 + r;
        if (rg >= M) rg = M - 1;
        floatx4 v = *(const floatx4*)(A + (size_t)rg * 128 + c4 * 4);
        unsigned long long d =
            ((unsigned long long)pkbf2(v[2], v[3]) << 32) | pkbf2(v[0], v[1]);
        *(unsigned long long*)(&a_lds[r * 136 + c4 * 4]) = d;
    }
    __syncthreads();

    floatx4 acc[2][8] = {};
    #pragma unroll
    for (int ks = 0; ks < 4; ks++) {
        int ko = ks * 32 + quad * 8;
        shortx8 a0 = *(const shortx8*)(&a_lds[(w * 32 + low) * 136 + ko]);
        shortx8 a1 = *(const shortx8*)(&a_lds[(w * 32 + 16 + low) * 136 + ko]);
        #pragma unroll
        for (int nt = 0; nt < 8; nt++) {
            shortx8 b = *(const shortx8*)(&b_lds[(nt * 16 + low) * 136 + ko]);
            acc[0][nt] = MFMA16(a0, b, acc[0][nt]);
            acc[1][nt] = MFMA16(a1, b, acc[1][nt]);
        }
    }

    #pragma unroll
    for (int mt = 0; mt < 2; mt++) {
        #pragma unroll
        for (int nt = 0; nt < 8; nt++) {
            #pragma unroll
            for (int r = 0; r < 4; r++) {
                int row = rbase + mt * 16 + quad * 4 + r;
                if (row >= M) continue;
                int col = nt * 16 + low;
                outb[(size_t)row * 256 + col_off + col] = f2bf_fast(acc[mt][nt][r] + bias[col]);
            }
        }
    }
}

// ---------------------------------------------------------------------------
// Aggregation: 16 lanes per node, 4 nodes per wave, 16 nodes per block.
// Lane L owns dims [L*8, L*8+8). Head h = L>>1; dot reduced via 1 shfl_xor.
// Folding butterfly for the 8-col projection reduce.
// ---------------------------------------------------------------------------
__global__ __launch_bounds__(256) void agg_kernel(
    const unsigned short* __restrict__ q0,
    const char* __restrict__ kamv0,      // = ws + OFF_KAMV_D
    const int* __restrict__ counts, const int* __restrict__ slots,
    const float* __restrict__ skipb,
    const float* __restrict__ WaLs, const float* __restrict__ bfin,
    float* __restrict__ out)
{
    __shared__ float wals[1032];   // [c][j*16+L] transposed-interleaved + bfin
    for (int i = threadIdx.x; i < 1024; i += 256) {
        int c = i >> 7, rem = i & 127, j = rem >> 4, L = rem & 15;
        wals[i] = WaLs[(L * 8 + j) * 8 + c];
    }
    if (threadIdx.x < 8) wals[1024 + threadIdx.x] = bfin[threadIdx.x];
    __syncthreads();

    int lane = threadIdx.x & 63;
    int grp = lane >> 4;               // node sub-index within wave
    int L   = lane & 15;
    int n = blockIdx.x * 16 + (threadIdx.x >> 6) * 4 + grp;

    // q fragment: 8 dims at L*8 (bf16 -> f32)
    intx4 qv = *(const intx4*)(q0 + (size_t)n * 128 + L * 8);
    float qf[8];
    #pragma unroll
    for (int d = 0; d < 4; d++) {
        unsigned int u = (unsigned int)qv[d];
        qf[2 * d]     = __uint_as_float(u << 16);
        qf[2 * d + 1] = __uint_as_float(u & 0xffff0000u);
    }

    int cnt = counts[n];
    cnt = cnt < 0 ? 0 : (cnt > CAP ? CAP : cnt);
    int s0 = slots[(size_t)n * CAP + L];    // offsets for edges 0..15

    float acc[8] = {0, 0, 0, 0, 0, 0, 0, 0};
    float den = 0.0f;
    for (int i = 0; i < cnt; i++) {
        int off = __shfl(s0, (lane & 48) + (i & 15));
        if (__builtin_expect(i >= 16, 0)) off = slots[(size_t)n * CAP + i];
        const char* p = kamv0 + off;
        intx4 ku = *(const intx4*)(p + L * 16);
        intx4 mu = *(const intx4*)(p + 256 + L * 16);
        float ph = 0.0f;
        #pragma unroll
        for (int d = 0; d < 4; d++) {
            unsigned int u = (unsigned int)ku[d];
            ph += qf[2 * d]     * __uint_as_float(u << 16);
            ph += qf[2 * d + 1] * __uint_as_float(u & 0xffff0000u);
        }
        float pf = ph + __shfl_xor(ph, 1);        // full 16-dim head dot
        float wgt = __expf(fminf(pf, 60.0f));
        den += wgt;
        #pragma unroll
        for (int d = 0; d < 4; d++) {
            unsigned int u = (unsigned int)mu[d];
            acc[2 * d]     += wgt * __uint_as_float(u << 16);
            acc[2 * d + 1] += wgt * __uint_as_float(u & 0xffff0000u);
        }
    }
    float inv = 1.0f / fmaxf(den, 1e-16f);

    // gelu + 8-col projection partials (conflict-free LDS: banks j*16+L)
    float part[8] = {0, 0, 0, 0, 0, 0, 0, 0};
    #pragma unroll
    for (int j = 0; j < 8; j++) {
        float u = gelu_exact(acc[j] * inv);
        #pragma unroll
        for (int c = 0; c < 8; c++)
            part[c] += u * wals[c * 128 + j * 16 + L];
    }

    // folding butterfly reduce over 16 lanes: 8 -> 4 -> 2 -> 1, then xor 8
    bool b0 = lane & 1, b1 = lane & 2, b2 = lane & 4;
    float t1[4], t2[2], t3;
    #pragma unroll
    for (int k = 0; k < 4; k++) {
        float send = b0 ? part[k] : part[4 + k];
        float got  = __shfl_xor(send, 1);
        t1[k] = (b0 ? part[4 + k] : part[k]) + got;
    }
    #pragma unroll
    for (int k = 0; k < 2; k++) {
        float send = b1 ? t1[k] : t1[2 + k];
        float got  = __shfl_xor(send, 2);
        t2[k] = (b1 ? t1[2 + k] : t1[k]) + got;
    }
    {
        float send = b2 ? t2[0] : t2[1];
        float got  = __shfl_xor(send, 4);
        t3 = (b2 ? t2[1] : t2[0]) + got;
    }
    t3 += __shfl_xor(t3, 8);
    // lane L (<8) holds c = 4*(L&1) + 2*((L>>1)&1) + ((L>>2)&1)
    if (L < 8) {
        int c = 4 * (L & 1) + 2 * ((L >> 1) & 1) + ((L >> 2) & 1);
        out[(size_t)n * 8 + c] = t3 + skipb[(size_t)n * 8 + c] + wals[1024 + c];
    }
}

// ---------------------------------------------------------------------------
// Host launch
// ---------------------------------------------------------------------------
extern "C" void kernel_launch(void* const* d_in, const int* in_sizes, int n_in,
                              void* d_out, int out_size, void* d_ws, size_t ws_size,
                              hipStream_t stream) {
    (void)in_sizes; (void)n_in; (void)out_size; (void)ws_size;
    const float* x_movie    = (const float*)d_in[0];
    const float* x_director = (const float*)d_in[1];
    const float* x_actor    = (const float*)d_in[2];
    const int* src_dm = (const int*)d_in[3];
    const int* dst_dm = (const int*)d_in[4];
    const int* src_am = (const int*)d_in[5];
    const int* dst_am = (const int*)d_in[6];
    const float* Wpre_m = (const float*)d_in[11];
    const float* Wpre_d = (const float*)d_in[12];
    const float* Wpre_a = (const float*)d_in[13];
    const float* bpre   = (const float*)d_in[14];
    const float* Wk     = (const float*)d_in[15];
    const float* bk     = (const float*)d_in[16];
    const float* Wq     = (const float*)d_in[17];
    const float* bq     = (const float*)d_in[18];
    const float* Wv     = (const float*)d_in[19];
    const float* bv     = (const float*)d_in[20];
    const float* a_rel  = (const float*)d_in[21];
    const float* m_rel  = (const float*)d_in[22];
    const float* p_rel  = (const float*)d_in[23];
    const float* skip   = (const float*)d_in[24];
    const float* Wa     = (const float*)d_in[25];
    const float* ba     = (const float*)d_in[26];
    const float* Wlin   = (const float*)d_in[27];
    const float* blin   = (const float*)d_in[28];

    char* ws = (char*)d_ws;
    float* out = (float*)d_out;

    precompA<<<(67080 + NM + 255) / 256, 256, 0, stream>>>(
        Wk, bk, Wv, bv, Wa, ba, Wlin, blin,
        a_rel, m_rel, p_rel, skip, bpre, ws);
    precompB<<<403, 256, 0, stream>>>(Wpre_m, Wpre_d, Wpre_a, bpre,
                                      Wq, bq, Wlin, skip, ws);

    edge_scatter<<<(2 * EDG + 255) / 256, 256, 0, stream>>>(
        src_dm, dst_dm, src_am, dst_am,
        (int*)(ws + OFF_COUNTS), (int*)(ws + OFF_SLOTS));

    gemm_m<9, true><<<(NM + 127) / 128, 256, 0, stream>>>(
        x_movie, NM, (const unsigned short*)(ws + OFF_BT_Q),
        (const float*)(ws + OFF_BQ),
        (unsigned short*)(ws + OFF_Q0), 128, (float*)(ws + OFF_SKIPB));

    gemm_kamv<<<dim3((ND + 127) / 128 + (NA + 127) / 128, 2), 256, 0, stream>>>(
        x_director, x_actor,
        (const unsigned short*)(ws + OFF_BT_KAMV_D),
        (const unsigned short*)(ws + OFF_BT_KAMV_A),
        (const float*)(ws + OFF_B_KAMV_D), (const float*)(ws + OFF_B_KAMV_A),
        (unsigned short*)(ws + OFF_KAMV_D), (unsigned short*)(ws + OFF_KAMV_A));

    agg_kernel<<<NM / 16, 256, 0, stream>>>(
        (const unsigned short*)(ws + OFF_Q0),
        (const char*)(ws + OFF_KAMV_D),
        (const int*)(ws + OFF_COUNTS), (const int*)(ws + OFF_SLOTS),
        (const float*)(ws + OFF_SKIPB),
        (const float*)(ws + OFF_WALS), (const float*)(ws + OFF_BFIN), out);
}

// Round 7
// 398.364 us; speedup vs baseline: 1.1218x; 1.1218x over previous
//
#include <hip/hip_runtime.h>
#include <hip/hip_bf16.h>
#include <math.h>

// ---------------------------------------------------------------------------
// Problem constants
// ---------------------------------------------------------------------------
#define NM 100000
#define ND 20000
#define NA 50000
#define EDG 300000
#define CAP 32   // max in-degree slots per movie node (Poisson(6): P(>32)~1.6e-14)
#define NBLK_M 782   // (NM+127)/128

typedef __attribute__((ext_vector_type(8))) short shortx8;
typedef __attribute__((ext_vector_type(4))) float floatx4;
typedef __attribute__((ext_vector_type(4))) int intx4;

__device__ __forceinline__ float bf2f(unsigned int u) {
    return __uint_as_float(u << 16);
}
__device__ __forceinline__ unsigned short f2bf(float f) {   // RNE (precomp only)
    unsigned int x = __float_as_uint(f);
    unsigned int r = x + 0x7fffu + ((x >> 16) & 1u);
    return (unsigned short)(r >> 16);
}
__device__ __forceinline__ unsigned short f2bf_fast(float f) {  // round-half-up
    return (unsigned short)((__float_as_uint(f) + 0x8000u) >> 16);
}
// pack 2 f32 -> dword [bf16(a) | bf16(b)<<16] : 2 add + 1 v_perm
__device__ __forceinline__ unsigned int pkbf2(float a, float b) {
    return __builtin_amdgcn_perm(__float_as_uint(b) + 0x8000u,
                                 __float_as_uint(a) + 0x8000u,
                                 0x07060302u);
}
__device__ __forceinline__ float gelu_exact(float x) {
    return 0.5f * x * (1.0f + erff(x * 0.70710678118654752f));
}

// ---------------------------------------------------------------------------
// Workspace layout (bytes) — total ~78.4 MB
// ---------------------------------------------------------------------------
static const size_t OFF_BT_Q      = 0;          // 144x256 bf16 (Wq^T composed | skip cols | zero)
static const size_t OFF_BT_KAMV_D = 73728;      // 256x128 bf16 (rows 0-127 ka, 128-255 mv)
static const size_t OFF_BT_KAMV_A = 139264;     // 256x128 bf16
static const size_t OFF_WKA_D     = 204800;     // 128x128 f32 TRANSPOSED [nc][e]
static const size_t OFF_WVM_D     = 270336;     // 128x128 f32 T
static const size_t OFF_WKA_A     = 335872;     // 128x128 f32 T
static const size_t OFF_WVM_A     = 401408;     // 128x128 f32 T
static const size_t OFF_BQ        = 466944;     // 144 f32
static const size_t OFF_B_KAMV_D  = 467520;     // 256 f32
static const size_t OFF_B_KAMV_A  = 468544;     // 256 f32
static const size_t OFF_BKA_D     = 469568;     // 128 f32
static const size_t OFF_BVM_D     = 470080;     // 128 f32
static const size_t OFF_BKA_A     = 470592;     // 128 f32
static const size_t OFF_BVM_A     = 471104;     // 128 f32
static const size_t OFF_WALS      = 471616;     // 128x8 f32 (g·Wa[0]@Wlin)
static const size_t OFF_BFIN      = 475712;     // 8 f32
static const size_t OFF_Q0        = 524288;     // NM*128 bf16   (25.6 MB)
static const size_t OFF_SKIPB     = 26124288;   // NM*8 f32      (3.2 MB)
static const size_t OFF_WQT       = 26124288;   // 128x128 f32 — overlaps SKIPB:
                                                // written by precompA, read by prep_scat,
                                                // then gemm_all overwrites with skipb (stream-ordered)
static const size_t OFF_KAMV_D    = 29324288;   // ND*256 bf16   (10.24 MB)
static const size_t OFF_KAMV_A    = 39564288;   // NA*256 bf16   (25.6 MB)
static const size_t OFF_COUNTS    = 65164288;   // NM int32
static const size_t OFF_SLOTS     = 65564288;   // NM*CAP int32  (12.8 MB)
#define KAMV_A_DELTA 10240000   // OFF_KAMV_A - OFF_KAMV_D

// ---------------------------------------------------------------------------
// K0a: fold a_rel/m_rel/p·scale into Wk/Wv (stored TRANSPOSED [out][in]);
// transpose Wq; epilogue tables; zero counts
// ---------------------------------------------------------------------------
__global__ __launch_bounds__(256) void precompA(
    const float* __restrict__ Wk, const float* __restrict__ bk,
    const float* __restrict__ Wv, const float* __restrict__ bv,
    const float* __restrict__ Wa, const float* __restrict__ ba,
    const float* __restrict__ Wlin, const float* __restrict__ blin,
    const float* __restrict__ a_rel, const float* __restrict__ m_rel,
    const float* __restrict__ p_rel, const float* __restrict__ skip,
    const float* __restrict__ bpre, const float* __restrict__ Wq,
    char* __restrict__ ws)
{
    int tid = blockIdx.x * 256 + threadIdx.x;
    if (tid < 65536) {
        int mat = tid >> 14, rem = tid & 16383;
        int e = rem >> 7, hf = rem & 127, h = hf >> 4, f = hf & 15;
        const float* Wsrc; const float* R; float sc; float* dst;
        if (mat == 0)      { Wsrc = Wk + 16384; R = a_rel;        sc = p_rel[h]     * 0.25f; dst = (float*)(ws + OFF_WKA_D); }
        else if (mat == 1) { Wsrc = Wv + 16384; R = m_rel;        sc = 1.0f;                 dst = (float*)(ws + OFF_WVM_D); }
        else if (mat == 2) { Wsrc = Wk + 32768; R = a_rel + 2048; sc = p_rel[8 + h] * 0.25f; dst = (float*)(ws + OFF_WKA_A); }
        else               { Wsrc = Wv + 32768; R = m_rel + 2048; sc = 1.0f;                 dst = (float*)(ws + OFF_WVM_A); }
        float s = 0.0f;
        for (int d = 0; d < 16; d++)
            s += Wsrc[e * 128 + h * 16 + d] * R[h * 256 + d * 16 + f];
        dst[hf * 128 + e] = s * sc;          // TRANSPOSED store
    } else if (tid < 66048) {
        int idx = tid - 65536;
        int mat = idx >> 7, hf = idx & 127, h = hf >> 4, f = hf & 15;
        const float* bsrc; const float* R; float sc; float* dst;
        if (mat == 0)      { bsrc = bk + 128; R = a_rel;        sc = p_rel[h]     * 0.25f; dst = (float*)(ws + OFF_BKA_D); }
        else if (mat == 1) { bsrc = bv + 128; R = m_rel;        sc = 1.0f;                 dst = (float*)(ws + OFF_BVM_D); }
        else if (mat == 2) { bsrc = bk + 256; R = a_rel + 2048; sc = p_rel[8 + h] * 0.25f; dst = (float*)(ws + OFF_BKA_A); }
        else               { bsrc = bv + 256; R = m_rel + 2048; sc = 1.0f;                 dst = (float*)(ws + OFF_BVM_A); }
        float s = 0.0f;
        for (int d = 0; d < 16; d++)
            s += bsrc[h * 16 + d] * R[h * 256 + d * 16 + f];
        dst[hf] = s * sc;
    } else if (tid < 67072) {
        // WaLs[j][c] = g * sum_o Wa[0][j][o] * Wlin[o][c]
        int idx = tid - 66048;
        int j = idx >> 3, c = idx & 7;
        float g = 1.0f / (1.0f + __expf(-skip[0]));
        float s = 0.0f;
        for (int o = 0; o < 128; o++)
            s += Wa[j * 128 + o] * Wlin[o * 8 + c];
        ((float*)(ws + OFF_WALS))[j * 8 + c] = g * s;
    } else if (tid < 67080) {
        int c = tid - 67072;
        float g = 1.0f / (1.0f + __expf(-skip[0]));
        float s1 = 0.0f, s2 = 0.0f;
        for (int o = 0; o < 128; o++) {
            s1 += ba[o]   * Wlin[o * 8 + c];
            s2 += bpre[o] * Wlin[o * 8 + c];
        }
        ((float*)(ws + OFF_BFIN))[c] = g * s1 + (1.0f - g) * s2 + blin[c];
    } else if (tid < 83464) {
        // WqT[n][e] = Wq[0][e][n]
        int i = tid - 67080;
        int n = i >> 7, e = i & 127;
        ((float*)(ws + OFF_WQT))[n * 128 + e] = Wq[e * 128 + n];
    } else if (tid < 83464 + NM) {
        ((int*)(ws + OFF_COUNTS))[tid - 83464] = 0;   // zero edge counters
    }
}

// ---------------------------------------------------------------------------
// contiguous-dot helper: 128-elem dot of two 16B-aligned f32 streams
// ---------------------------------------------------------------------------
__device__ __forceinline__ float dot128(const float* __restrict__ a,
                                        const float* __restrict__ b) {
    const floatx4* x = (const floatx4*)a;
    const floatx4* y = (const floatx4*)b;
    float s = 0.0f;
    #pragma unroll
    for (int i = 0; i < 32; i++) {
        floatx4 u = x[i], v = y[i];
        s += u[0] * v[0] + u[1] * v[1] + u[2] * v[2] + u[3] * v[3];
    }
    return s;
}

// ---------------------------------------------------------------------------
// K0b + edge scatter fused (independent work, block-range split).
// Blocks [0, 2344): scatter.  Blocks [2344, 2747): precompB.
// ---------------------------------------------------------------------------
__global__ __launch_bounds__(256) void prep_scat(
    const int* __restrict__ src_dm, const int* __restrict__ dst_dm,
    const int* __restrict__ src_am, const int* __restrict__ dst_am,
    const float* __restrict__ Wpre_m, const float* __restrict__ Wpre_d,
    const float* __restrict__ Wpre_a, const float* __restrict__ bpre,
    const float* __restrict__ bq, const float* __restrict__ Wlin,
    const float* __restrict__ skip,
    char* __restrict__ ws)
{
    if (blockIdx.x < 2344) {
        int t = blockIdx.x * 256 + threadIdx.x;
        if (t >= 2 * EDG) return;
        int src, dst, delta;
        if (t < EDG) { src = src_dm[t];       dst = dst_dm[t];       delta = 0; }
        else         { src = src_am[t - EDG]; dst = dst_am[t - EDG]; delta = KAMV_A_DELTA; }
        int* counts = (int*)(ws + OFF_COUNTS);
        int* slots  = (int*)(ws + OFF_SLOTS);
        int pos = atomicAdd(&counts[dst], 1);
        if (pos < CAP) slots[(size_t)dst * CAP + pos] = src * 512 + delta;
        return;
    }
    int tid = (blockIdx.x - 2344) * 256 + threadIdx.x;
    const float* WKA_D = (const float*)(ws + OFF_WKA_D);
    const float* WVM_D = (const float*)(ws + OFF_WVM_D);
    const float* WKA_A = (const float*)(ws + OFF_WKA_A);
    const float* WVM_A = (const float*)(ws + OFF_WVM_A);
    const float* WqT   = (const float*)(ws + OFF_WQT);

    if (tid < 36864) {
        int n = tid >> 8, c = tid & 255;
        float s = 0.0f;
        if (n < 128) {
            s = dot128(Wpre_m + c * 128, WqT + n * 128);
        } else if (n < 136) {
            int cc = n - 128;
            float g = 1.0f / (1.0f + __expf(-skip[0]));
            for (int e = 0; e < 128; e++)
                s += Wpre_m[c * 128 + e] * Wlin[e * 8 + cc];
            s *= (1.0f - g);
        }
        ((unsigned short*)(ws + OFF_BT_Q))[n * 256 + c] = f2bf(s);
    } else if (tid < 69632) {
        int idx = tid - 36864;
        int nrow = idx >> 7, c = idx & 127;
        const float* WfT = (nrow < 128) ? WKA_D : WVM_D;
        int nc = nrow & 127;
        float s = dot128(Wpre_d + c * 128, WfT + nc * 128);
        ((unsigned short*)(ws + OFF_BT_KAMV_D))[nrow * 128 + c] = f2bf(s);
    } else if (tid < 102400) {
        int idx = tid - 69632;
        int nrow = idx >> 7, c = idx & 127;
        const float* WfT = (nrow < 128) ? WKA_A : WVM_A;
        int nc = nrow & 127;
        float s = dot128(Wpre_a + c * 128, WfT + nc * 128);
        ((unsigned short*)(ws + OFF_BT_KAMV_A))[nrow * 128 + c] = f2bf(s);
    } else if (tid < 102544) {
        int n = tid - 102400;
        float s = 0.0f;
        if (n < 128) s = dot128(bpre, WqT + n * 128) + bq[n];
        ((float*)(ws + OFF_BQ))[n] = s;
    } else if (tid < 102800) {
        int nrow = tid - 102544;
        const float* WfT = (nrow < 128) ? WKA_D : WVM_D;
        const float* bf_ = (nrow < 128) ? (const float*)(ws + OFF_BKA_D) : (const float*)(ws + OFF_BVM_D);
        int nc = nrow & 127;
        ((float*)(ws + OFF_B_KAMV_D))[nrow] = dot128(bpre + 128, WfT + nc * 128) + bf_[nc];
    } else if (tid < 103056) {
        int nrow = tid - 102800;
        const float* WfT = (nrow < 128) ? WKA_A : WVM_A;
        const float* bf_ = (nrow < 128) ? (const float*)(ws + OFF_BKA_A) : (const float*)(ws + OFF_BVM_A);
        int nc = nrow & 127;
        ((float*)(ws + OFF_B_KAMV_A))[nrow] = dot128(bpre + 256, WfT + nc * 128) + bf_[nc];
    }
}

// ---------------------------------------------------------------------------
// ALL GEMMs in one dispatch. Blocks [0,782): movie q0+skip (K=256, NT=9).
// Blocks [782,1878): director/actor ka|mv panels (K=128, NT=8).
// Staging fully unrolled: loads batched to registers, then LDS writes.
// ---------------------------------------------------------------------------
#define MFMA16(a, b, c) __builtin_amdgcn_mfma_f32_16x16x32_bf16(a, b, c, 0, 0, 0)

__global__ __launch_bounds__(256, 2) void gemm_all(
    const float* __restrict__ xm, const float* __restrict__ xd,
    const float* __restrict__ xa,
    const unsigned short* __restrict__ btq,
    const unsigned short* __restrict__ btd,
    const unsigned short* __restrict__ bta,
    const float* __restrict__ bq,
    const float* __restrict__ bbd, const float* __restrict__ bba,
    unsigned short* __restrict__ q0, float* __restrict__ skipb,
    unsigned short* __restrict__ outd, unsigned short* __restrict__ outa)
{
    __shared__ unsigned short a_lds[128 * 136];   // 34816 B
    __shared__ unsigned short b_lds[144 * 136];   // 39168 B
    int tid = threadIdx.x;
    int w = tid >> 6, lane = tid & 63;
    int quad = lane >> 4, low = lane & 15;
    int bx = blockIdx.x;

    if (bx < NBLK_M) {
        // ---------------- movie: q0 + skip, K=256 ----------------
        int row0 = bx * 128;
        floatx4 acc[2][9] = {};
        for (int hfi = 0; hfi < 2; hfi++) {
            if (hfi) __syncthreads();
            intx4 bvv[9];
            #pragma unroll
            for (int it = 0; it < 9; it++) {
                int idx = it * 256 + tid, n = idx >> 4, ch = idx & 15;
                bvv[it] = *(const intx4*)&btq[(size_t)n * 256 + hfi * 128 + ch * 8];
            }
            floatx4 av[16];
            #pragma unroll
            for (int it = 0; it < 16; it++) {
                int f = it * 256 + tid, r = f >> 5, c4 = f & 31;
                int rg = row0 + r; if (rg >= NM) rg = NM - 1;
                av[it] = *(const floatx4*)(xm + (size_t)rg * 256 + hfi * 128 + c4 * 4);
            }
            #pragma unroll
            for (int it = 0; it < 9; it++) {
                int idx = it * 256 + tid, n = idx >> 4, ch = idx & 15;
                *(intx4*)&b_lds[n * 136 + ch * 8] = bvv[it];
            }
            #pragma unroll
            for (int it = 0; it < 16; it++) {
                int f = it * 256 + tid, r = f >> 5, c4 = f & 31;
                unsigned long long d =
                    ((unsigned long long)pkbf2(av[it][2], av[it][3]) << 32) |
                    pkbf2(av[it][0], av[it][1]);
                *(unsigned long long*)&a_lds[r * 136 + c4 * 4] = d;
            }
            __syncthreads();
            #pragma unroll
            for (int ks = 0; ks < 4; ks++) {
                int ko = ks * 32 + quad * 8;
                shortx8 a0 = *(const shortx8*)&a_lds[(w * 32 + low) * 136 + ko];
                shortx8 a1 = *(const shortx8*)&a_lds[(w * 32 + 16 + low) * 136 + ko];
                #pragma unroll
                for (int nt = 0; nt < 9; nt++) {
                    shortx8 b = *(const shortx8*)&b_lds[(nt * 16 + low) * 136 + ko];
                    acc[0][nt] = MFMA16(a0, b, acc[0][nt]);
                    acc[1][nt] = MFMA16(a1, b, acc[1][nt]);
                }
            }
        }
        int rb = row0 + w * 32;
        #pragma unroll
        for (int mt = 0; mt < 2; mt++) {
            #pragma unroll
            for (int nt = 0; nt < 9; nt++) {
                #pragma unroll
                for (int r = 0; r < 4; r++) {
                    int row = rb + mt * 16 + quad * 4 + r;
                    if (row >= NM) continue;
                    int col = nt * 16 + low;
                    float v = acc[mt][nt][r] + bq[col];
                    if (nt == 8) {
                        if (low < 8) skipb[(size_t)row * 8 + low] = v;
                    } else {
                        q0[(size_t)row * 128 + col] = f2bf_fast(v);
                    }
                }
            }
        }
    } else {
        // ---------------- director/actor ka|mv, K=128 ----------------
        int rem = bx - NBLK_M;
        const float* A; const unsigned short* BT; const float* bias;
        unsigned short* outb; int M, kbx, cofs;
        if (rem < 157)      { A = xd; BT = btd;             bias = bbd;       outb = outd; M = ND; kbx = rem;       cofs = 0;   }
        else if (rem < 314) { A = xd; BT = btd + 128 * 128; bias = bbd + 128; outb = outd; M = ND; kbx = rem - 157; cofs = 128; }
        else if (rem < 705) { A = xa; BT = bta;             bias = bba;       outb = outa; M = NA; kbx = rem - 314; cofs = 0;   }
        else                { A = xa; BT = bta + 128 * 128; bias = bba + 128; outb = outa; M = NA; kbx = rem - 705; cofs = 128; }
        int row0 = kbx * 128;

        intx4 bvv[8];
        #pragma unroll
        for (int it = 0; it < 8; it++) {
            int idx = it * 256 + tid, n = idx >> 4, ch = idx & 15;
            bvv[it] = *(const intx4*)&BT[(size_t)n * 128 + ch * 8];
        }
        floatx4 av[16];
        #pragma unroll
        for (int it = 0; it < 16; it++) {
            int f = it * 256 + tid, r = f >> 5, c4 = f & 31;
            int rg = row0 + r; if (rg >= M) rg = M - 1;
            av[it] = *(const floatx4*)(A + (size_t)rg * 128 + c4 * 4);
        }
        #pragma unroll
        for (int it = 0; it < 8; it++) {
            int idx = it * 256 + tid, n = idx >> 4, ch = idx & 15;
            *(intx4*)&b_lds[n * 136 + ch * 8] = bvv[it];
        }
        #pragma unroll
        for (int it = 0; it < 16; it++) {
            int f = it * 256 + tid, r = f >> 5, c4 = f & 31;
            unsigned long long d =
                ((unsigned long long)pkbf2(av[it][2], av[it][3]) << 32) |
                pkbf2(av[it][0], av[it][1]);
            *(unsigned long long*)&a_lds[r * 136 + c4 * 4] = d;
        }
        __syncthreads();

        floatx4 acc[2][8] = {};
        #pragma unroll
        for (int ks = 0; ks < 4; ks++) {
            int ko = ks * 32 + quad * 8;
            shortx8 a0 = *(const shortx8*)&a_lds[(w * 32 + low) * 136 + ko];
            shortx8 a1 = *(const shortx8*)&a_lds[(w * 32 + 16 + low) * 136 + ko];
            #pragma unroll
            for (int nt = 0; nt < 8; nt++) {
                shortx8 b = *(const shortx8*)&b_lds[(nt * 16 + low) * 136 + ko];
                acc[0][nt] = MFMA16(a0, b, acc[0][nt]);
                acc[1][nt] = MFMA16(a1, b, acc[1][nt]);
            }
        }
        int rb = row0 + w * 32;
        #pragma unroll
        for (int mt = 0; mt < 2; mt++) {
            #pragma unroll
            for (int nt = 0; nt < 8; nt++) {
                #pragma unroll
                for (int r = 0; r < 4; r++) {
                    int row = rb + mt * 16 + quad * 4 + r;
                    if (row >= M) continue;
                    int col = nt * 16 + low;
                    outb[(size_t)row * 256 + cofs + col] = f2bf_fast(acc[mt][nt][r] + bias[col]);
                }
            }
        }
    }
}

// ---------------------------------------------------------------------------
// Aggregation: 16 lanes per node, 4 nodes per wave, 16 nodes per block.
// ---------------------------------------------------------------------------
__global__ __launch_bounds__(256) void agg_kernel(
    const unsigned short* __restrict__ q0,
    const char* __restrict__ kamv0,      // = ws + OFF_KAMV_D
    const int* __restrict__ counts, const int* __restrict__ slots,
    const float* __restrict__ skipb,
    const float* __restrict__ WaLs, const float* __restrict__ bfin,
    float* __restrict__ out)
{
    __shared__ float wals[1032];   // [c][j*16+L] transposed-interleaved + bfin
    for (int i = threadIdx.x; i < 1024; i += 256) {
        int c = i >> 7, rem = i & 127, j = rem >> 4, L = rem & 15;
        wals[i] = WaLs[(L * 8 + j) * 8 + c];
    }
    if (threadIdx.x < 8) wals[1024 + threadIdx.x] = bfin[threadIdx.x];
    __syncthreads();

    int lane = threadIdx.x & 63;
    int grp = lane >> 4;
    int L   = lane & 15;
    int n = blockIdx.x * 16 + (threadIdx.x >> 6) * 4 + grp;

    intx4 qv = *(const intx4*)(q0 + (size_t)n * 128 + L * 8);
    float qf[8];
    #pragma unroll
    for (int d = 0; d < 4; d++) {
        unsigned int u = (unsigned int)qv[d];
        qf[2 * d]     = __uint_as_float(u << 16);
        qf[2 * d + 1] = __uint_as_float(u & 0xffff0000u);
    }

    int cnt = counts[n];
    cnt = cnt < 0 ? 0 : (cnt > CAP ? CAP : cnt);
    int s0 = slots[(size_t)n * CAP + L];

    float acc[8] = {0, 0, 0, 0, 0, 0, 0, 0};
    float den = 0.0f;
    for (int i = 0; i < cnt; i++) {
        int off = __shfl(s0, (lane & 48) + (i & 15));
        if (__builtin_expect(i >= 16, 0)) off = slots[(size_t)n * CAP + i];
        const char* p = kamv0 + off;
        intx4 ku = *(const intx4*)(p + L * 16);
        intx4 mu = *(const intx4*)(p + 256 + L * 16);
        float ph = 0.0f;
        #pragma unroll
        for (int d = 0; d < 4; d++) {
            unsigned int u = (unsigned int)ku[d];
            ph += qf[2 * d]     * __uint_as_float(u << 16);
            ph += qf[2 * d + 1] * __uint_as_float(u & 0xffff0000u);
        }
        float pf = ph + __shfl_xor(ph, 1);
        float wgt = __expf(fminf(pf, 60.0f));
        den += wgt;
        #pragma unroll
        for (int d = 0; d < 4; d++) {
            unsigned int u = (unsigned int)mu[d];
            acc[2 * d]     += wgt * __uint_as_float(u << 16);
            acc[2 * d + 1] += wgt * __uint_as_float(u & 0xffff0000u);
        }
    }
    float inv = 1.0f / fmaxf(den, 1e-16f);

    float part[8] = {0, 0, 0, 0, 0, 0, 0, 0};
    #pragma unroll
    for (int j = 0; j < 8; j++) {
        float u = gelu_exact(acc[j] * inv);
        #pragma unroll
        for (int c = 0; c < 8; c++)
            part[c] += u * wals[c * 128 + j * 16 + L];
    }

    bool b0 = lane & 1, b1 = lane & 2, b2 = lane & 4;
    float t1[4], t2[2], t3;
    #pragma unroll
    for (int k = 0; k < 4; k++) {
        float send = b0 ? part[k] : part[4 + k];
        float got  = __shfl_xor(send, 1);
        t1[k] = (b0 ? part[4 + k] : part[k]) + got;
    }
    #pragma unroll
    for (int k = 0; k < 2; k++) {
        float send = b1 ? t1[k] : t1[2 + k];
        float got  = __shfl_xor(send, 2);
        t2[k] = (b1 ? t1[2 + k] : t1[k]) + got;
    }
    {
        float send = b2 ? t2[0] : t2[1];
        float got  = __shfl_xor(send, 4);
        t3 = (b2 ? t2[1] : t2[0]) + got;
    }
    t3 += __shfl_xor(t3, 8);
    if (L < 8) {
        int c = 4 * (L & 1) + 2 * ((L >> 1) & 1) + ((L >> 2) & 1);
        out[(size_t)n * 8 + c] = t3 + skipb[(size_t)n * 8 + c] + wals[1024 + c];
    }
}

// ---------------------------------------------------------------------------
// Host launch — 4 dispatches
// ---------------------------------------------------------------------------
extern "C" void kernel_launch(void* const* d_in, const int* in_sizes, int n_in,
                              void* d_out, int out_size, void* d_ws, size_t ws_size,
                              hipStream_t stream) {
    (void)in_sizes; (void)n_in; (void)out_size; (void)ws_size;
    const float* x_movie    = (const float*)d_in[0];
    const float* x_director = (const float*)d_in[1];
    const float* x_actor    = (const float*)d_in[2];
    const int* src_dm = (const int*)d_in[3];
    const int* dst_dm = (const int*)d_in[4];
    const int* src_am = (const int*)d_in[5];
    const int* dst_am = (const int*)d_in[6];
    const float* Wpre_m = (const float*)d_in[11];
    const float* Wpre_d = (const float*)d_in[12];
    const float* Wpre_a = (const float*)d_in[13];
    const float* bpre   = (const float*)d_in[14];
    const float* Wk     = (const float*)d_in[15];
    const float* bk     = (const float*)d_in[16];
    const float* Wq     = (const float*)d_in[17];
    const float* bq     = (const float*)d_in[18];
    const float* Wv     = (const float*)d_in[19];
    const float* bv     = (const float*)d_in[20];
    const float* a_rel  = (const float*)d_in[21];
    const float* m_rel  = (const float*)d_in[22];
    const float* p_rel  = (const float*)d_in[23];
    const float* skip   = (const float*)d_in[24];
    const float* Wa     = (const float*)d_in[25];
    const float* ba     = (const float*)d_in[26];
    const float* Wlin   = (const float*)d_in[27];
    const float* blin   = (const float*)d_in[28];

    char* ws = (char*)d_ws;
    float* out = (float*)d_out;

    precompA<<<(83464 + NM + 255) / 256, 256, 0, stream>>>(
        Wk, bk, Wv, bv, Wa, ba, Wlin, blin,
        a_rel, m_rel, p_rel, skip, bpre, Wq, ws);

    prep_scat<<<2344 + 403, 256, 0, stream>>>(
        src_dm, dst_dm, src_am, dst_am,
        Wpre_m, Wpre_d, Wpre_a, bpre, bq, Wlin, skip, ws);

    gemm_all<<<NBLK_M + 1096, 256, 0, stream>>>(
        x_movie, x_director, x_actor,
        (const unsigned short*)(ws + OFF_BT_Q),
        (const unsigned short*)(ws + OFF_BT_KAMV_D),
        (const unsigned short*)(ws + OFF_BT_KAMV_A),
        (const float*)(ws + OFF_BQ),
        (const float*)(ws + OFF_B_KAMV_D), (const float*)(ws + OFF_B_KAMV_A),
        (unsigned short*)(ws + OFF_Q0), (float*)(ws + OFF_SKIPB),
        (unsigned short*)(ws + OFF_KAMV_D), (unsigned short*)(ws + OFF_KAMV_A));

    agg_kernel<<<NM / 16, 256, 0, stream>>>(
        (const unsigned short*)(ws + OFF_Q0),
        (const char*)(ws + OFF_KAMV_D),
        (const int*)(ws + OFF_COUNTS), (const int*)(ws + OFF_SLOTS),
        (const float*)(ws + OFF_SKIPB),
        (const float*)(ws + OFF_WALS), (const float*)(ws + OFF_BFIN), out);
}

// Round 8
// 396.007 us; speedup vs baseline: 1.1285x; 1.0060x over previous
//
#include <hip/hip_runtime.h>
#include <hip/hip_bf16.h>
#include <math.h>

// ---------------------------------------------------------------------------
// Problem constants
// ---------------------------------------------------------------------------
#define NM 100000
#define ND 20000
#define NA 50000
#define EDG 300000
#define CAP 32    // max in-degree slots per movie node (Poisson(6): P(>32)~1.6e-14)
#define NBLK_M 1563   // ceil(NM/64)
#define NBLK_D 313    // ceil(ND/64)
#define NBLK_A 782    // ceil(NA/64)

typedef __attribute__((ext_vector_type(8))) short shortx8;
typedef __attribute__((ext_vector_type(4))) float floatx4;
typedef __attribute__((ext_vector_type(4))) int intx4;

__device__ __forceinline__ float bf2f(unsigned int u) {
    return __uint_as_float(u << 16);
}
__device__ __forceinline__ unsigned short f2bf(float f) {   // RNE (precomp only)
    unsigned int x = __float_as_uint(f);
    unsigned int r = x + 0x7fffu + ((x >> 16) & 1u);
    return (unsigned short)(r >> 16);
}
__device__ __forceinline__ unsigned short f2bf_fast(float f) {  // round-half-up
    return (unsigned short)((__float_as_uint(f) + 0x8000u) >> 16);
}
// pack 2 f32 -> dword [bf16(a) | bf16(b)<<16] : 2 add + 1 v_perm
__device__ __forceinline__ unsigned int pkbf2(float a, float b) {
    return __builtin_amdgcn_perm(__float_as_uint(b) + 0x8000u,
                                 __float_as_uint(a) + 0x8000u,
                                 0x07060302u);
}
__device__ __forceinline__ float gelu_exact(float x) {
    return 0.5f * x * (1.0f + erff(x * 0.70710678118654752f));
}

// ---------------------------------------------------------------------------
// Workspace layout (bytes) — total ~78.4 MB
// ---------------------------------------------------------------------------
static const size_t OFF_BT_Q      = 0;          // [2][144][128] bf16, HALF-MAJOR
static const size_t OFF_BT_KAMV_D = 73728;      // 256x128 bf16 (rows 0-127 ka, 128-255 mv)
static const size_t OFF_BT_KAMV_A = 139264;     // 256x128 bf16
static const size_t OFF_WKA_D     = 204800;     // 128x128 f32 TRANSPOSED [nc][e]
static const size_t OFF_WVM_D     = 270336;     // 128x128 f32 T
static const size_t OFF_WKA_A     = 335872;     // 128x128 f32 T
static const size_t OFF_WVM_A     = 401408;     // 128x128 f32 T
static const size_t OFF_BQ        = 466944;     // 144 f32
static const size_t OFF_B_KAMV_D  = 467520;     // 256 f32
static const size_t OFF_B_KAMV_A  = 468544;     // 256 f32
static const size_t OFF_BKA_D     = 469568;     // 128 f32
static const size_t OFF_BVM_D     = 470080;     // 128 f32
static const size_t OFF_BKA_A     = 470592;     // 128 f32
static const size_t OFF_BVM_A     = 471104;     // 128 f32
static const size_t OFF_WALS      = 471616;     // 128x8 f32 (g·Wa[0]@Wlin)
static const size_t OFF_BFIN      = 475712;     // 8 f32
static const size_t OFF_Q0        = 524288;     // NM*128 bf16   (25.6 MB)
static const size_t OFF_SKIPB     = 26124288;   // NM*8 f32      (3.2 MB)
static const size_t OFF_WQT       = 26124288;   // 128x128 f32 — overlaps SKIPB:
                                                // precompA writes, prep_scat reads,
                                                // gemm_all overwrites later (stream-ordered)
static const size_t OFF_KAMV_D    = 29324288;   // ND*256 bf16   (10.24 MB)
static const size_t OFF_KAMV_A    = 39564288;   // NA*256 bf16   (25.6 MB)
static const size_t OFF_COUNTS    = 65164288;   // NM int32
static const size_t OFF_SLOTS     = 65564288;   // NM*CAP int32  (12.8 MB)
#define KAMV_A_DELTA 10240000   // OFF_KAMV_A - OFF_KAMV_D

// ---------------------------------------------------------------------------
// K0a: fold a_rel/m_rel/p·scale into Wk/Wv (stored TRANSPOSED [out][in]);
// transpose Wq; epilogue tables; zero counts
// ---------------------------------------------------------------------------
__global__ __launch_bounds__(256) void precompA(
    const float* __restrict__ Wk, const float* __restrict__ bk,
    const float* __restrict__ Wv, const float* __restrict__ bv,
    const float* __restrict__ Wa, const float* __restrict__ ba,
    const float* __restrict__ Wlin, const float* __restrict__ blin,
    const float* __restrict__ a_rel, const float* __restrict__ m_rel,
    const float* __restrict__ p_rel, const float* __restrict__ skip,
    const float* __restrict__ bpre, const float* __restrict__ Wq,
    char* __restrict__ ws)
{
    int tid = blockIdx.x * 256 + threadIdx.x;
    if (tid < 65536) {
        int mat = tid >> 14, rem = tid & 16383;
        int e = rem >> 7, hf = rem & 127, h = hf >> 4, f = hf & 15;
        const float* Wsrc; const float* R; float sc; float* dst;
        if (mat == 0)      { Wsrc = Wk + 16384; R = a_rel;        sc = p_rel[h]     * 0.25f; dst = (float*)(ws + OFF_WKA_D); }
        else if (mat == 1) { Wsrc = Wv + 16384; R = m_rel;        sc = 1.0f;                 dst = (float*)(ws + OFF_WVM_D); }
        else if (mat == 2) { Wsrc = Wk + 32768; R = a_rel + 2048; sc = p_rel[8 + h] * 0.25f; dst = (float*)(ws + OFF_WKA_A); }
        else               { Wsrc = Wv + 32768; R = m_rel + 2048; sc = 1.0f;                 dst = (float*)(ws + OFF_WVM_A); }
        float s = 0.0f;
        for (int d = 0; d < 16; d++)
            s += Wsrc[e * 128 + h * 16 + d] * R[h * 256 + d * 16 + f];
        dst[hf * 128 + e] = s * sc;          // TRANSPOSED store
    } else if (tid < 66048) {
        int idx = tid - 65536;
        int mat = idx >> 7, hf = idx & 127, h = hf >> 4, f = hf & 15;
        const float* bsrc; const float* R; float sc; float* dst;
        if (mat == 0)      { bsrc = bk + 128; R = a_rel;        sc = p_rel[h]     * 0.25f; dst = (float*)(ws + OFF_BKA_D); }
        else if (mat == 1) { bsrc = bv + 128; R = m_rel;        sc = 1.0f;                 dst = (float*)(ws + OFF_BVM_D); }
        else if (mat == 2) { bsrc = bk + 256; R = a_rel + 2048; sc = p_rel[8 + h] * 0.25f; dst = (float*)(ws + OFF_BKA_A); }
        else               { bsrc = bv + 256; R = m_rel + 2048; sc = 1.0f;                 dst = (float*)(ws + OFF_BVM_A); }
        float s = 0.0f;
        for (int d = 0; d < 16; d++)
            s += bsrc[h * 16 + d] * R[h * 256 + d * 16 + f];
        dst[hf] = s * sc;
    } else if (tid < 67072) {
        // WaLs[j][c] = g * sum_o Wa[0][j][o] * Wlin[o][c]
        int idx = tid - 66048;
        int j = idx >> 3, c = idx & 7;
        float g = 1.0f / (1.0f + __expf(-skip[0]));
        float s = 0.0f;
        for (int o = 0; o < 128; o++)
            s += Wa[j * 128 + o] * Wlin[o * 8 + c];
        ((float*)(ws + OFF_WALS))[j * 8 + c] = g * s;
    } else if (tid < 67080) {
        int c = tid - 67072;
        float g = 1.0f / (1.0f + __expf(-skip[0]));
        float s1 = 0.0f, s2 = 0.0f;
        for (int o = 0; o < 128; o++) {
            s1 += ba[o]   * Wlin[o * 8 + c];
            s2 += bpre[o] * Wlin[o * 8 + c];
        }
        ((float*)(ws + OFF_BFIN))[c] = g * s1 + (1.0f - g) * s2 + blin[c];
    } else if (tid < 83464) {
        // WqT[n][e] = Wq[0][e][n]
        int i = tid - 67080;
        int n = i >> 7, e = i & 127;
        ((float*)(ws + OFF_WQT))[n * 128 + e] = Wq[e * 128 + n];
    } else if (tid < 83464 + NM) {
        ((int*)(ws + OFF_COUNTS))[tid - 83464] = 0;   // zero edge counters
    }
}

// ---------------------------------------------------------------------------
// contiguous-dot helper: 128-elem dot of two 16B-aligned f32 streams
// ---------------------------------------------------------------------------
__device__ __forceinline__ float dot128(const float* __restrict__ a,
                                        const float* __restrict__ b) {
    const floatx4* x = (const floatx4*)a;
    const floatx4* y = (const floatx4*)b;
    float s = 0.0f;
    #pragma unroll
    for (int i = 0; i < 32; i++) {
        floatx4 u = x[i], v = y[i];
        s += u[0] * v[0] + u[1] * v[1] + u[2] * v[2] + u[3] * v[3];
    }
    return s;
}

// ---------------------------------------------------------------------------
// K0b + edge scatter fused (independent work, block-range split).
// Blocks [0, 2344): scatter.  Blocks [2344, 2747): precompB.
// ---------------------------------------------------------------------------
__global__ __launch_bounds__(256) void prep_scat(
    const int* __restrict__ src_dm, const int* __restrict__ dst_dm,
    const int* __restrict__ src_am, const int* __restrict__ dst_am,
    const float* __restrict__ Wpre_m, const float* __restrict__ Wpre_d,
    const float* __restrict__ Wpre_a, const float* __restrict__ bpre,
    const float* __restrict__ bq, const float* __restrict__ Wlin,
    const float* __restrict__ skip,
    char* __restrict__ ws)
{
    if (blockIdx.x < 2344) {
        int t = blockIdx.x * 256 + threadIdx.x;
        if (t >= 2 * EDG) return;
        int src, dst, delta;
        if (t < EDG) { src = src_dm[t];       dst = dst_dm[t];       delta = 0; }
        else         { src = src_am[t - EDG]; dst = dst_am[t - EDG]; delta = KAMV_A_DELTA; }
        int* counts = (int*)(ws + OFF_COUNTS);
        int* slots  = (int*)(ws + OFF_SLOTS);
        int pos = atomicAdd(&counts[dst], 1);
        if (pos < CAP) slots[(size_t)dst * CAP + pos] = src * 512 + delta;
        return;
    }
    int tid = (blockIdx.x - 2344) * 256 + threadIdx.x;
    const float* WKA_D = (const float*)(ws + OFF_WKA_D);
    const float* WVM_D = (const float*)(ws + OFF_WVM_D);
    const float* WKA_A = (const float*)(ws + OFF_WKA_A);
    const float* WVM_A = (const float*)(ws + OFF_WVM_A);
    const float* WqT   = (const float*)(ws + OFF_WQT);

    if (tid < 36864) {
        int n = tid >> 8, c = tid & 255;
        float s = 0.0f;
        if (n < 128) {
            s = dot128(Wpre_m + c * 128, WqT + n * 128);
        } else if (n < 136) {
            int cc = n - 128;
            float g = 1.0f / (1.0f + __expf(-skip[0]));
            for (int e = 0; e < 128; e++)
                s += Wpre_m[c * 128 + e] * Wlin[e * 8 + cc];
            s *= (1.0f - g);
        }
        // HALF-MAJOR store: [c>>7][n][c&127]
        ((unsigned short*)(ws + OFF_BT_Q))[(c >> 7) * 18432 + n * 128 + (c & 127)] = f2bf(s);
    } else if (tid < 69632) {
        int idx = tid - 36864;
        int nrow = idx >> 7, c = idx & 127;
        const float* WfT = (nrow < 128) ? WKA_D : WVM_D;
        int nc = nrow & 127;
        float s = dot128(Wpre_d + c * 128, WfT + nc * 128);
        ((unsigned short*)(ws + OFF_BT_KAMV_D))[nrow * 128 + c] = f2bf(s);
    } else if (tid < 102400) {
        int idx = tid - 69632;
        int nrow = idx >> 7, c = idx & 127;
        const float* WfT = (nrow < 128) ? WKA_A : WVM_A;
        int nc = nrow & 127;
        float s = dot128(Wpre_a + c * 128, WfT + nc * 128);
        ((unsigned short*)(ws + OFF_BT_KAMV_A))[nrow * 128 + c] = f2bf(s);
    } else if (tid < 102544) {
        int n = tid - 102400;
        float s = 0.0f;
        if (n < 128) s = dot128(bpre, WqT + n * 128) + bq[n];
        ((float*)(ws + OFF_BQ))[n] = s;
    } else if (tid < 102800) {
        int nrow = tid - 102544;
        const float* WfT = (nrow < 128) ? WKA_D : WVM_D;
        const float* bf_ = (nrow < 128) ? (const float*)(ws + OFF_BKA_D) : (const float*)(ws + OFF_BVM_D);
        int nc = nrow & 127;
        ((float*)(ws + OFF_B_KAMV_D))[nrow] = dot128(bpre + 128, WfT + nc * 128) + bf_[nc];
    } else if (tid < 103056) {
        int nrow = tid - 102800;
        const float* WfT = (nrow < 128) ? WKA_A : WVM_A;
        const float* bf_ = (nrow < 128) ? (const float*)(ws + OFF_BKA_A) : (const float*)(ws + OFF_BVM_A);
        int nc = nrow & 127;
        ((float*)(ws + OFF_B_KAMV_A))[nrow] = dot128(bpre + 256, WfT + nc * 128) + bf_[nc];
    }
}

// ---------------------------------------------------------------------------
// ALL GEMMs, 64-row tiles, software-pipelined.
// Blocks [0,1563): movie q0+skip (K=256 in 2 halves, 9 col-tiles).
// Blocks [1563,2658): director/actor, K=128, both 128-col panels per block.
// ---------------------------------------------------------------------------
#define MFMA16(a, b, c) __builtin_amdgcn_mfma_f32_16x16x32_bf16(a, b, c, 0, 0, 0)

__global__ __launch_bounds__(256, 2) void gemm_all(
    const float* __restrict__ xm, const float* __restrict__ xd,
    const float* __restrict__ xa,
    const unsigned short* __restrict__ btq,   // [2][144][128]
    const unsigned short* __restrict__ btd,
    const unsigned short* __restrict__ bta,
    const float* __restrict__ bq,
    const float* __restrict__ bbd, const float* __restrict__ bba,
    unsigned short* __restrict__ q0, float* __restrict__ skipb,
    unsigned short* __restrict__ outd, unsigned short* __restrict__ outa)
{
    __shared__ unsigned short a_lds[64 * 136];    // 17408 B
    __shared__ unsigned short b_lds[144 * 136];   // 39168 B
    int tid = threadIdx.x;
    int w = tid >> 6, lane = tid & 63;
    int quad = lane >> 4, low = lane & 15;
    int bx = blockIdx.x;

    if (bx < NBLK_M) {
        // ---------------- movie: q0 + skip, K=256, pipelined halves --------
        int row0 = bx * 64;
        // half-0 loads
        intx4 bv[9];
        #pragma unroll
        for (int it = 0; it < 9; it++) {
            int idx = it * 256 + tid, n = idx >> 4, ch = idx & 15;
            bv[it] = *(const intx4*)&btq[(size_t)n * 128 + ch * 8];
        }
        floatx4 av[8];
        #pragma unroll
        for (int it = 0; it < 8; it++) {
            int f = it * 256 + tid, r = f >> 5, c4 = f & 31;
            int rg = row0 + r; if (rg >= NM) rg = NM - 1;
            av[it] = *(const floatx4*)(xm + (size_t)rg * 256 + c4 * 4);
        }
        #pragma unroll
        for (int it = 0; it < 9; it++) {
            int idx = it * 256 + tid, n = idx >> 4, ch = idx & 15;
            *(intx4*)&b_lds[n * 136 + ch * 8] = bv[it];
        }
        #pragma unroll
        for (int it = 0; it < 8; it++) {
            int f = it * 256 + tid, r = f >> 5, c4 = f & 31;
            unsigned long long d =
                ((unsigned long long)pkbf2(av[it][2], av[it][3]) << 32) |
                pkbf2(av[it][0], av[it][1]);
            *(unsigned long long*)&a_lds[r * 136 + c4 * 4] = d;
        }
        __syncthreads();

        // issue half-1 loads before MFMA on half 0
        intx4 bv1[9];
        #pragma unroll
        for (int it = 0; it < 9; it++) {
            int idx = it * 256 + tid, n = idx >> 4, ch = idx & 15;
            bv1[it] = *(const intx4*)&btq[18432 + (size_t)n * 128 + ch * 8];
        }
        floatx4 av1[8];
        #pragma unroll
        for (int it = 0; it < 8; it++) {
            int f = it * 256 + tid, r = f >> 5, c4 = f & 31;
            int rg = row0 + r; if (rg >= NM) rg = NM - 1;
            av1[it] = *(const floatx4*)(xm + (size_t)rg * 256 + 128 + c4 * 4);
        }

        floatx4 acc[9] = {};
        #pragma unroll
        for (int ks = 0; ks < 4; ks++) {
            int ko = ks * 32 + quad * 8;
            shortx8 a0 = *(const shortx8*)&a_lds[(w * 16 + low) * 136 + ko];
            #pragma unroll
            for (int nt = 0; nt < 9; nt++) {
                shortx8 b = *(const shortx8*)&b_lds[(nt * 16 + low) * 136 + ko];
                acc[nt] = MFMA16(a0, b, acc[nt]);
            }
        }
        __syncthreads();
        #pragma unroll
        for (int it = 0; it < 9; it++) {
            int idx = it * 256 + tid, n = idx >> 4, ch = idx & 15;
            *(intx4*)&b_lds[n * 136 + ch * 8] = bv1[it];
        }
        #pragma unroll
        for (int it = 0; it < 8; it++) {
            int f = it * 256 + tid, r = f >> 5, c4 = f & 31;
            unsigned long long d =
                ((unsigned long long)pkbf2(av1[it][2], av1[it][3]) << 32) |
                pkbf2(av1[it][0], av1[it][1]);
            *(unsigned long long*)&a_lds[r * 136 + c4 * 4] = d;
        }
        __syncthreads();
        #pragma unroll
        for (int ks = 0; ks < 4; ks++) {
            int ko = ks * 32 + quad * 8;
            shortx8 a0 = *(const shortx8*)&a_lds[(w * 16 + low) * 136 + ko];
            #pragma unroll
            for (int nt = 0; nt < 9; nt++) {
                shortx8 b = *(const shortx8*)&b_lds[(nt * 16 + low) * 136 + ko];
                acc[nt] = MFMA16(a0, b, acc[nt]);
            }
        }

        int rb = row0 + w * 16;
        #pragma unroll
        for (int nt = 0; nt < 9; nt++) {
            #pragma unroll
            for (int r = 0; r < 4; r++) {
                int row = rb + quad * 4 + r;
                if (row >= NM) continue;
                int col = nt * 16 + low;
                float v = acc[nt][r] + bq[col];
                if (nt == 8) {
                    if (low < 8) skipb[(size_t)row * 8 + low] = v;
                } else {
                    q0[(size_t)row * 128 + col] = f2bf_fast(v);
                }
            }
        }
    } else {
        // ------------- director/actor: K=128, both panels per block --------
        int rem = bx - NBLK_M;
        const float* A; const unsigned short* BT; const float* bias;
        unsigned short* outb; int M, kbx;
        if (rem < NBLK_D) { A = xd; BT = btd; bias = bbd; outb = outd; M = ND; kbx = rem; }
        else              { A = xa; BT = bta; bias = bba; outb = outa; M = NA; kbx = rem - NBLK_D; }
        int row0 = kbx * 64;

        intx4 bv[8];
        #pragma unroll
        for (int it = 0; it < 8; it++) {
            int idx = it * 256 + tid, n = idx >> 4, ch = idx & 15;
            bv[it] = *(const intx4*)&BT[(size_t)n * 128 + ch * 8];
        }
        floatx4 av[8];
        #pragma unroll
        for (int it = 0; it < 8; it++) {
            int f = it * 256 + tid, r = f >> 5, c4 = f & 31;
            int rg = row0 + r; if (rg >= M) rg = M - 1;
            av[it] = *(const floatx4*)(A + (size_t)rg * 128 + c4 * 4);
        }
        #pragma unroll
        for (int it = 0; it < 8; it++) {
            int idx = it * 256 + tid, n = idx >> 4, ch = idx & 15;
            *(intx4*)&b_lds[n * 136 + ch * 8] = bv[it];
        }
        #pragma unroll
        for (int it = 0; it < 8; it++) {
            int f = it * 256 + tid, r = f >> 5, c4 = f & 31;
            unsigned long long d =
                ((unsigned long long)pkbf2(av[it][2], av[it][3]) << 32) |
                pkbf2(av[it][0], av[it][1]);
            *(unsigned long long*)&a_lds[r * 136 + c4 * 4] = d;
        }
        __syncthreads();

        // issue panel-1 B loads before panel-0 MFMA
        intx4 bv1[8];
        #pragma unroll
        for (int it = 0; it < 8; it++) {
            int idx = it * 256 + tid, n = idx >> 4, ch = idx & 15;
            bv1[it] = *(const intx4*)&BT[16384 + (size_t)n * 128 + ch * 8];
        }

        int rb = row0 + w * 16;
        {
            floatx4 acc[8] = {};
            #pragma unroll
            for (int ks = 0; ks < 4; ks++) {
                int ko = ks * 32 + quad * 8;
                shortx8 a0 = *(const shortx8*)&a_lds[(w * 16 + low) * 136 + ko];
                #pragma unroll
                for (int nt = 0; nt < 8; nt++) {
                    shortx8 b = *(const shortx8*)&b_lds[(nt * 16 + low) * 136 + ko];
                    acc[nt] = MFMA16(a0, b, acc[nt]);
                }
            }
            #pragma unroll
            for (int nt = 0; nt < 8; nt++) {
                #pragma unroll
                for (int r = 0; r < 4; r++) {
                    int row = rb + quad * 4 + r;
                    if (row >= M) continue;
                    int col = nt * 16 + low;
                    outb[(size_t)row * 256 + col] = f2bf_fast(acc[nt][r] + bias[col]);
                }
            }
        }
        __syncthreads();
        #pragma unroll
        for (int it = 0; it < 8; it++) {
            int idx = it * 256 + tid, n = idx >> 4, ch = idx & 15;
            *(intx4*)&b_lds[n * 136 + ch * 8] = bv1[it];
        }
        __syncthreads();
        {
            floatx4 acc[8] = {};
            #pragma unroll
            for (int ks = 0; ks < 4; ks++) {
                int ko = ks * 32 + quad * 8;
                shortx8 a0 = *(const shortx8*)&a_lds[(w * 16 + low) * 136 + ko];
                #pragma unroll
                for (int nt = 0; nt < 8; nt++) {
                    shortx8 b = *(const shortx8*)&b_lds[(nt * 16 + low) * 136 + ko];
                    acc[nt] = MFMA16(a0, b, acc[nt]);
                }
            }
            #pragma unroll
            for (int nt = 0; nt < 8; nt++) {
                #pragma unroll
                for (int r = 0; r < 4; r++) {
                    int row = rb + quad * 4 + r;
                    if (row >= M) continue;
                    int col = nt * 16 + low;
                    outb[(size_t)row * 256 + 128 + col] = f2bf_fast(acc[nt][r] + bias[128 + col]);
                }
            }
        }
    }
}

// ---------------------------------------------------------------------------
// Aggregation: 16 lanes/node, 4 nodes/wave, 1-deep edge prefetch.
// ---------------------------------------------------------------------------
__global__ __launch_bounds__(256) void agg_kernel(
    const unsigned short* __restrict__ q0,
    const char* __restrict__ kamv0,      // = ws + OFF_KAMV_D
    const int* __restrict__ counts, const int* __restrict__ slots,
    const float* __restrict__ skipb,
    const float* __restrict__ WaLs, const float* __restrict__ bfin,
    float* __restrict__ out)
{
    __shared__ float wals[1032];   // [c][j*16+L] transposed-interleaved + bfin
    for (int i = threadIdx.x; i < 1024; i += 256) {
        int c = i >> 7, rem = i & 127, j = rem >> 4, L = rem & 15;
        wals[i] = WaLs[(L * 8 + j) * 8 + c];
    }
    if (threadIdx.x < 8) wals[1024 + threadIdx.x] = bfin[threadIdx.x];
    __syncthreads();

    int lane = threadIdx.x & 63;
    int grp = lane >> 4;
    int L   = lane & 15;
    int n = blockIdx.x * 16 + (threadIdx.x >> 6) * 4 + grp;

    intx4 qv = *(const intx4*)(q0 + (size_t)n * 128 + L * 8);
    float qf[8];
    #pragma unroll
    for (int d = 0; d < 4; d++) {
        unsigned int u = (unsigned int)qv[d];
        qf[2 * d]     = __uint_as_float(u << 16);
        qf[2 * d + 1] = __uint_as_float(u & 0xffff0000u);
    }

    int cnt = counts[n];
    cnt = cnt < 0 ? 0 : (cnt > CAP ? CAP : cnt);
    int s0 = slots[(size_t)n * CAP + L];

    float acc[8] = {0, 0, 0, 0, 0, 0, 0, 0};
    float den = 0.0f;
    if (cnt > 0) {
        int off0 = __shfl(s0, lane & 48);
        const char* p = kamv0 + off0;
        intx4 ku = *(const intx4*)(p + L * 16);
        intx4 mu = *(const intx4*)(p + 256 + L * 16);
        for (int i = 0; i < cnt; i++) {
            // prefetch edge i+1 (clamped) before consuming edge i
            int inext = (i + 1 < cnt) ? i + 1 : i;
            int offn = __shfl(s0, (lane & 48) + (inext & 15));
            if (__builtin_expect(inext >= 16, 0)) offn = slots[(size_t)n * CAP + inext];
            const char* pn = kamv0 + offn;
            intx4 kun = *(const intx4*)(pn + L * 16);
            intx4 mun = *(const intx4*)(pn + 256 + L * 16);

            float ph = 0.0f;
            #pragma unroll
            for (int d = 0; d < 4; d++) {
                unsigned int u = (unsigned int)ku[d];
                ph += qf[2 * d]     * __uint_as_float(u << 16);
                ph += qf[2 * d + 1] * __uint_as_float(u & 0xffff0000u);
            }
            float pf = ph + __shfl_xor(ph, 1);
            float wgt = __expf(fminf(pf, 60.0f));
            den += wgt;
            #pragma unroll
            for (int d = 0; d < 4; d++) {
                unsigned int u = (unsigned int)mu[d];
                acc[2 * d]     += wgt * __uint_as_float(u << 16);
                acc[2 * d + 1] += wgt * __uint_as_float(u & 0xffff0000u);
            }
            ku = kun; mu = mun;
        }
    }
    float inv = 1.0f / fmaxf(den, 1e-16f);

    float part[8] = {0, 0, 0, 0, 0, 0, 0, 0};
    #pragma unroll
    for (int j = 0; j < 8; j++) {
        float u = gelu_exact(acc[j] * inv);
        #pragma unroll
        for (int c = 0; c < 8; c++)
            part[c] += u * wals[c * 128 + j * 16 + L];
    }

    bool b0 = lane & 1, b1 = lane & 2, b2 = lane & 4;
    float t1[4], t2[2], t3;
    #pragma unroll
    for (int k = 0; k < 4; k++) {
        float send = b0 ? part[k] : part[4 + k];
        float got  = __shfl_xor(send, 1);
        t1[k] = (b0 ? part[4 + k] : part[k]) + got;
    }
    #pragma unroll
    for (int k = 0; k < 2; k++) {
        float send = b1 ? t1[k] : t1[2 + k];
        float got  = __shfl_xor(send, 2);
        t2[k] = (b1 ? t1[2 + k] : t1[k]) + got;
    }
    {
        float send = b2 ? t2[0] : t2[1];
        float got  = __shfl_xor(send, 4);
        t3 = (b2 ? t2[1] : t2[0]) + got;
    }
    t3 += __shfl_xor(t3, 8);
    if (L < 8) {
        int c = 4 * (L & 1) + 2 * ((L >> 1) & 1) + ((L >> 2) & 1);
        out[(size_t)n * 8 + c] = t3 + skipb[(size_t)n * 8 + c] + wals[1024 + c];
    }
}

// ---------------------------------------------------------------------------
// Host launch — 4 dispatches
// ---------------------------------------------------------------------------
extern "C" void kernel_launch(void* const* d_in, const int* in_sizes, int n_in,
                              void* d_out, int out_size, void* d_ws, size_t ws_size,
                              hipStream_t stream) {
    (void)in_sizes; (void)n_in; (void)out_size; (void)ws_size;
    const float* x_movie    = (const float*)d_in[0];
    const float* x_director = (const float*)d_in[1];
    const float* x_actor    = (const float*)d_in[2];
    const int* src_dm = (const int*)d_in[3];
    const int* dst_dm = (const int*)d_in[4];
    const int* src_am = (const int*)d_in[5];
    const int* dst_am = (const int*)d_in[6];
    const float* Wpre_m = (const float*)d_in[11];
    const float* Wpre_d = (const float*)d_in[12];
    const float* Wpre_a = (const float*)d_in[13];
    const float* bpre   = (const float*)d_in[14];
    const float* Wk     = (const float*)d_in[15];
    const float* bk     = (const float*)d_in[16];
    const float* Wq     = (const float*)d_in[17];
    const float* bq     = (const float*)d_in[18];
    const float* Wv     = (const float*)d_in[19];
    const float* bv     = (const float*)d_in[20];
    const float* a_rel  = (const float*)d_in[21];
    const float* m_rel  = (const float*)d_in[22];
    const float* p_rel  = (const float*)d_in[23];
    const float* skip   = (const float*)d_in[24];
    const float* Wa     = (const float*)d_in[25];
    const float* ba     = (const float*)d_in[26];
    const float* Wlin   = (const float*)d_in[27];
    const float* blin   = (const float*)d_in[28];

    char* ws = (char*)d_ws;
    float* out = (float*)d_out;

    precompA<<<(83464 + NM + 255) / 256, 256, 0, stream>>>(
        Wk, bk, Wv, bv, Wa, ba, Wlin, blin,
        a_rel, m_rel, p_rel, skip, bpre, Wq, ws);

    prep_scat<<<2344 + 403, 256, 0, stream>>>(
        src_dm, dst_dm, src_am, dst_am,
        Wpre_m, Wpre_d, Wpre_a, bpre, bq, Wlin, skip, ws);

    gemm_all<<<NBLK_M + NBLK_D + NBLK_A, 256, 0, stream>>>(
        x_movie, x_director, x_actor,
        (const unsigned short*)(ws + OFF_BT_Q),
        (const unsigned short*)(ws + OFF_BT_KAMV_D),
        (const unsigned short*)(ws + OFF_BT_KAMV_A),
        (const float*)(ws + OFF_BQ),
        (const float*)(ws + OFF_B_KAMV_D), (const float*)(ws + OFF_B_KAMV_A),
        (unsigned short*)(ws + OFF_Q0), (float*)(ws + OFF_SKIPB),
        (unsigned short*)(ws + OFF_KAMV_D), (unsigned short*)(ws + OFF_KAMV_A));

    agg_kernel<<<NM / 16, 256, 0, stream>>>(
        (const unsigned short*)(ws + OFF_Q0),
        (const char*)(ws + OFF_KAMV_D),
        (const int*)(ws + OFF_COUNTS), (const int*)(ws + OFF_SLOTS),
        (const float*)(ws + OFF_SKIPB),
        (const float*)(ws + OFF_WALS), (const float*)(ws + OFF_BFIN), out);
}

// Round 9
// 394.429 us; speedup vs baseline: 1.1330x; 1.0040x over previous
//
#include <hip/hip_runtime.h>
#include <hip/hip_bf16.h>
#include <math.h>

// ---------------------------------------------------------------------------
// Problem constants
// ---------------------------------------------------------------------------
#define NM 100000
#define ND 20000
#define NA 50000
#define EDG 300000
#define CAP 32    // max in-degree slots per movie node (Poisson(6): P(>32)~1.6e-14)

#define NT_M   3125   // movie row-tiles of 32 (exact: 100000/32)
#define NT_D   625    // director tiles (exact)
#define NT_K   2188   // director+actor tiles (625 + 1563)
#define T_M    7      // tiles per movie block
#define T_K    7      // tiles per kamv block
#define BLK_M  447    // ceil(3125/7)
#define BLK_K  313    // ceil(2188/7)

typedef __attribute__((ext_vector_type(8))) short shortx8;
typedef __attribute__((ext_vector_type(4))) float floatx4;
typedef __attribute__((ext_vector_type(4))) int intx4;

__device__ __forceinline__ float bf2f(unsigned int u) {
    return __uint_as_float(u << 16);
}
__device__ __forceinline__ unsigned short f2bf(float f) {   // RNE (precomp only)
    unsigned int x = __float_as_uint(f);
    unsigned int r = x + 0x7fffu + ((x >> 16) & 1u);
    return (unsigned short)(r >> 16);
}
__device__ __forceinline__ unsigned short f2bf_fast(float f) {  // round-half-up
    return (unsigned short)((__float_as_uint(f) + 0x8000u) >> 16);
}
// pack 2 f32 -> dword [bf16(a) | bf16(b)<<16] : 2 add + 1 v_perm
__device__ __forceinline__ unsigned int pkbf2(float a, float b) {
    return __builtin_amdgcn_perm(__float_as_uint(b) + 0x8000u,
                                 __float_as_uint(a) + 0x8000u,
                                 0x07060302u);
}
__device__ __forceinline__ float gelu_exact(float x) {
    return 0.5f * x * (1.0f + erff(x * 0.70710678118654752f));
}

// ---------------------------------------------------------------------------
// Workspace layout (bytes)
// ---------------------------------------------------------------------------
static const size_t OFF_BT_Q      = 0;          // [2][144][128] bf16, HALF-MAJOR
static const size_t OFF_BT_KAMV_D = 73728;      // 256x128 bf16 (rows 0-127 ka, 128-255 mv)
static const size_t OFF_BT_KAMV_A = 139264;     // 256x128 bf16
static const size_t OFF_WKA_D     = 204800;     // 128x128 f32 TRANSPOSED [nc][e]
static const size_t OFF_WVM_D     = 270336;     // 128x128 f32 T
static const size_t OFF_WKA_A     = 335872;     // 128x128 f32 T
static const size_t OFF_WVM_A     = 401408;     // 128x128 f32 T
static const size_t OFF_BQ        = 466944;     // 144 f32
static const size_t OFF_B_KAMV_D  = 467520;     // 256 f32
static const size_t OFF_B_KAMV_A  = 468544;     // 256 f32
static const size_t OFF_BKA_D     = 469568;     // 128 f32
static const size_t OFF_BVM_D     = 470080;     // 128 f32
static const size_t OFF_BKA_A     = 470592;     // 128 f32
static const size_t OFF_BVM_A     = 471104;     // 128 f32
static const size_t OFF_WALS      = 471616;     // 128x8 f32 (g·Wa[0]@Wlin)
static const size_t OFF_BFIN      = 475712;     // 8 f32
static const size_t OFF_Q0        = 524288;     // NM*128 bf16   (25.6 MB)
static const size_t OFF_SKIPB     = 26124288;   // NM*8 f32      (3.2 MB)
static const size_t OFF_WQT       = 26124288;   // 128x128 f32 — overlaps SKIPB
static const size_t OFF_KAMV_D    = 29324288;   // ND*256 bf16   (10.24 MB)
static const size_t OFF_KAMV_A    = 39564288;   // NA*256 bf16   (25.6 MB)
static const size_t OFF_COUNTS    = 65164288;   // NM int32
static const size_t OFF_SLOTS     = 65564288;   // NM*CAP int32  (12.8 MB)
#define KAMV_A_DELTA 10240000   // OFF_KAMV_A - OFF_KAMV_D

// ---------------------------------------------------------------------------
// K0a: fold a_rel/m_rel/p·scale into Wk/Wv (stored TRANSPOSED); transpose Wq;
// epilogue tables; zero counts
// ---------------------------------------------------------------------------
__global__ __launch_bounds__(256) void precompA(
    const float* __restrict__ Wk, const float* __restrict__ bk,
    const float* __restrict__ Wv, const float* __restrict__ bv,
    const float* __restrict__ Wa, const float* __restrict__ ba,
    const float* __restrict__ Wlin, const float* __restrict__ blin,
    const float* __restrict__ a_rel, const float* __restrict__ m_rel,
    const float* __restrict__ p_rel, const float* __restrict__ skip,
    const float* __restrict__ bpre, const float* __restrict__ Wq,
    char* __restrict__ ws)
{
    int tid = blockIdx.x * 256 + threadIdx.x;
    if (tid < 65536) {
        int mat = tid >> 14, rem = tid & 16383;
        int e = rem >> 7, hf = rem & 127, h = hf >> 4, f = hf & 15;
        const float* Wsrc; const float* R; float sc; float* dst;
        if (mat == 0)      { Wsrc = Wk + 16384; R = a_rel;        sc = p_rel[h]     * 0.25f; dst = (float*)(ws + OFF_WKA_D); }
        else if (mat == 1) { Wsrc = Wv + 16384; R = m_rel;        sc = 1.0f;                 dst = (float*)(ws + OFF_WVM_D); }
        else if (mat == 2) { Wsrc = Wk + 32768; R = a_rel + 2048; sc = p_rel[8 + h] * 0.25f; dst = (float*)(ws + OFF_WKA_A); }
        else               { Wsrc = Wv + 32768; R = m_rel + 2048; sc = 1.0f;                 dst = (float*)(ws + OFF_WVM_A); }
        float s = 0.0f;
        for (int d = 0; d < 16; d++)
            s += Wsrc[e * 128 + h * 16 + d] * R[h * 256 + d * 16 + f];
        dst[hf * 128 + e] = s * sc;          // TRANSPOSED store
    } else if (tid < 66048) {
        int idx = tid - 65536;
        int mat = idx >> 7, hf = idx & 127, h = hf >> 4, f = hf & 15;
        const float* bsrc; const float* R; float sc; float* dst;
        if (mat == 0)      { bsrc = bk + 128; R = a_rel;        sc = p_rel[h]     * 0.25f; dst = (float*)(ws + OFF_BKA_D); }
        else if (mat == 1) { bsrc = bv + 128; R = m_rel;        sc = 1.0f;                 dst = (float*)(ws + OFF_BVM_D); }
        else if (mat == 2) { bsrc = bk + 256; R = a_rel + 2048; sc = p_rel[8 + h] * 0.25f; dst = (float*)(ws + OFF_BKA_A); }
        else               { bsrc = bv + 256; R = m_rel + 2048; sc = 1.0f;                 dst = (float*)(ws + OFF_BVM_A); }
        float s = 0.0f;
        for (int d = 0; d < 16; d++)
            s += bsrc[h * 16 + d] * R[h * 256 + d * 16 + f];
        dst[hf] = s * sc;
    } else if (tid < 67072) {
        // WaLs[j][c] = g * sum_o Wa[0][j][o] * Wlin[o][c]
        int idx = tid - 66048;
        int j = idx >> 3, c = idx & 7;
        float g = 1.0f / (1.0f + __expf(-skip[0]));
        float s = 0.0f;
        for (int o = 0; o < 128; o++)
            s += Wa[j * 128 + o] * Wlin[o * 8 + c];
        ((float*)(ws + OFF_WALS))[j * 8 + c] = g * s;
    } else if (tid < 67080) {
        int c = tid - 67072;
        float g = 1.0f / (1.0f + __expf(-skip[0]));
        float s1 = 0.0f, s2 = 0.0f;
        for (int o = 0; o < 128; o++) {
            s1 += ba[o]   * Wlin[o * 8 + c];
            s2 += bpre[o] * Wlin[o * 8 + c];
        }
        ((float*)(ws + OFF_BFIN))[c] = g * s1 + (1.0f - g) * s2 + blin[c];
    } else if (tid < 83464) {
        // WqT[n][e] = Wq[0][e][n]
        int i = tid - 67080;
        int n = i >> 7, e = i & 127;
        ((float*)(ws + OFF_WQT))[n * 128 + e] = Wq[e * 128 + n];
    } else if (tid < 83464 + NM) {
        ((int*)(ws + OFF_COUNTS))[tid - 83464] = 0;   // zero edge counters
    }
}

// ---------------------------------------------------------------------------
// contiguous-dot helper: 128-elem dot of two 16B-aligned f32 streams
// ---------------------------------------------------------------------------
__device__ __forceinline__ float dot128(const float* __restrict__ a,
                                        const float* __restrict__ b) {
    const floatx4* x = (const floatx4*)a;
    const floatx4* y = (const floatx4*)b;
    float s = 0.0f;
    #pragma unroll
    for (int i = 0; i < 32; i++) {
        floatx4 u = x[i], v = y[i];
        s += u[0] * v[0] + u[1] * v[1] + u[2] * v[2] + u[3] * v[3];
    }
    return s;
}

// ---------------------------------------------------------------------------
// K0b + edge scatter fused (independent work, block-range split).
// Blocks [0, 2344): scatter.  Blocks [2344, 2747): precompB.
// ---------------------------------------------------------------------------
__global__ __launch_bounds__(256) void prep_scat(
    const int* __restrict__ src_dm, const int* __restrict__ dst_dm,
    const int* __restrict__ src_am, const int* __restrict__ dst_am,
    const float* __restrict__ Wpre_m, const float* __restrict__ Wpre_d,
    const float* __restrict__ Wpre_a, const float* __restrict__ bpre,
    const float* __restrict__ bq, const float* __restrict__ Wlin,
    const float* __restrict__ skip,
    char* __restrict__ ws)
{
    if (blockIdx.x < 2344) {
        int t = blockIdx.x * 256 + threadIdx.x;
        if (t >= 2 * EDG) return;
        int src, dst, delta;
        if (t < EDG) { src = src_dm[t];       dst = dst_dm[t];       delta = 0; }
        else         { src = src_am[t - EDG]; dst = dst_am[t - EDG]; delta = KAMV_A_DELTA; }
        int* counts = (int*)(ws + OFF_COUNTS);
        int* slots  = (int*)(ws + OFF_SLOTS);
        int pos = atomicAdd(&counts[dst], 1);
        if (pos < CAP) slots[(size_t)dst * CAP + pos] = src * 512 + delta;
        return;
    }
    int tid = (blockIdx.x - 2344) * 256 + threadIdx.x;
    const float* WKA_D = (const float*)(ws + OFF_WKA_D);
    const float* WVM_D = (const float*)(ws + OFF_WVM_D);
    const float* WKA_A = (const float*)(ws + OFF_WKA_A);
    const float* WVM_A = (const float*)(ws + OFF_WVM_A);
    const float* WqT   = (const float*)(ws + OFF_WQT);

    if (tid < 36864) {
        int n = tid >> 8, c = tid & 255;
        float s = 0.0f;
        if (n < 128) {
            s = dot128(Wpre_m + c * 128, WqT + n * 128);
        } else if (n < 136) {
            int cc = n - 128;
            float g = 1.0f / (1.0f + __expf(-skip[0]));
            for (int e = 0; e < 128; e++)
                s += Wpre_m[c * 128 + e] * Wlin[e * 8 + cc];
            s *= (1.0f - g);
        }
        // HALF-MAJOR store: [c>>7][n][c&127]
        ((unsigned short*)(ws + OFF_BT_Q))[(c >> 7) * 18432 + n * 128 + (c & 127)] = f2bf(s);
    } else if (tid < 69632) {
        int idx = tid - 36864;
        int nrow = idx >> 7, c = idx & 127;
        const float* WfT = (nrow < 128) ? WKA_D : WVM_D;
        int nc = nrow & 127;
        float s = dot128(Wpre_d + c * 128, WfT + nc * 128);
        ((unsigned short*)(ws + OFF_BT_KAMV_D))[nrow * 128 + c] = f2bf(s);
    } else if (tid < 102400) {
        int idx = tid - 69632;
        int nrow = idx >> 7, c = idx & 127;
        const float* WfT = (nrow < 128) ? WKA_A : WVM_A;
        int nc = nrow & 127;
        float s = dot128(Wpre_a + c * 128, WfT + nc * 128);
        ((unsigned short*)(ws + OFF_BT_KAMV_A))[nrow * 128 + c] = f2bf(s);
    } else if (tid < 102544) {
        int n = tid - 102400;
        float s = 0.0f;
        if (n < 128) s = dot128(bpre, WqT + n * 128) + bq[n];
        ((float*)(ws + OFF_BQ))[n] = s;
    } else if (tid < 102800) {
        int nrow = tid - 102544;
        const float* WfT = (nrow < 128) ? WKA_D : WVM_D;
        const float* bf_ = (nrow < 128) ? (const float*)(ws + OFF_BKA_D) : (const float*)(ws + OFF_BVM_D);
        int nc = nrow & 127;
        ((float*)(ws + OFF_B_KAMV_D))[nrow] = dot128(bpre + 128, WfT + nc * 128) + bf_[nc];
    } else if (tid < 103056) {
        int nrow = tid - 102800;
        const float* WfT = (nrow < 128) ? WKA_A : WVM_A;
        const float* bf_ = (nrow < 128) ? (const float*)(ws + OFF_BKA_A) : (const float*)(ws + OFF_BVM_A);
        int nc = nrow & 127;
        ((float*)(ws + OFF_B_KAMV_A))[nrow] = dot128(bpre + 256, WfT + nc * 128) + bf_[nc];
    }
}

// ---------------------------------------------------------------------------
// Persistent-tile pipelined GEMM. 760 blocks, 3 blocks/CU (47.9 KB LDS),
// every block co-resident. Per phase: regs->LDS, sync, issue next loads,
// MFMA from LDS (loads fly during MFMA). 32-row tiles, 4 waves split
// (row-slab s) x (nt-group g).
// Blocks [0,447): movie, 7 tiles (K=256, 2 halves/tile, 9 nt).
// Blocks [447,760): director/actor, 7 tiles (K=128, 2 panels/tile, 8 nt).
// ---------------------------------------------------------------------------
#define MFMA16(a, b, c) __builtin_amdgcn_mfma_f32_16x16x32_bf16(a, b, c, 0, 0, 0)

__global__ __launch_bounds__(256, 3) void gemm_all(
    const float* __restrict__ xm, const float* __restrict__ xd,
    const float* __restrict__ xa,
    const unsigned short* __restrict__ btq,   // [2][144][128]
    const unsigned short* __restrict__ btd,
    const unsigned short* __restrict__ bta,
    const float* __restrict__ bq,
    const float* __restrict__ bbd, const float* __restrict__ bba,
    unsigned short* __restrict__ q0, float* __restrict__ skipb,
    unsigned short* __restrict__ outd, unsigned short* __restrict__ outa)
{
    __shared__ unsigned short a_lds[32 * 136];    //  8704 B
    __shared__ unsigned short b_lds[144 * 136];   // 39168 B
    int tid = threadIdx.x;
    int w = tid >> 6, lane = tid & 63;
    int quad = lane >> 4, low = lane & 15;
    int g = w >> 1, s = w & 1;
    int bx = blockIdx.x;

    if (bx < BLK_M) {
        // =================== movie: q0 + skip ===================
        int tbase = bx * T_M;
        floatx4 av[4];
        intx4 bv[9];
        // preload phase (t=tbase, h=0)
        {
            int row0 = (tbase < NT_M ? tbase : NT_M - 1) * 32;
            #pragma unroll
            for (int it = 0; it < 4; it++) {
                int f = it * 256 + tid, r = f >> 5, c4 = f & 31;
                av[it] = *(const floatx4*)(xm + (size_t)(row0 + r) * 256 + c4 * 4);
            }
            #pragma unroll
            for (int it = 0; it < 9; it++) {
                int idx = it * 256 + tid, n = idx >> 4, ch = idx & 15;
                bv[it] = *(const intx4*)&btq[(size_t)n * 128 + ch * 8];
            }
        }
        for (int t = 0; t < T_M; t++) {
            int tcur = tbase + t;
            if (tcur >= NT_M) break;
            int row0 = tcur * 32;
            floatx4 acc[5] = {};
            #pragma unroll
            for (int h = 0; h < 2; h++) {
                __syncthreads();
                #pragma unroll
                for (int it = 0; it < 4; it++) {
                    int f = it * 256 + tid, r = f >> 5, c4 = f & 31;
                    unsigned long long d =
                        ((unsigned long long)pkbf2(av[it][2], av[it][3]) << 32) |
                        pkbf2(av[it][0], av[it][1]);
                    *(unsigned long long*)&a_lds[r * 136 + c4 * 4] = d;
                }
                #pragma unroll
                for (int it = 0; it < 9; it++) {
                    int idx = it * 256 + tid, n = idx >> 4, ch = idx & 15;
                    *(intx4*)&b_lds[n * 136 + ch * 8] = bv[it];
                }
                __syncthreads();
                // issue next-phase loads (overlap MFMA)
                {
                    int ntile = (h == 0) ? tcur : (tcur + 1 < NT_M ? tcur + 1 : NT_M - 1);
                    int nh = 1 - h;
                    int nrow0 = ntile * 32;
                    #pragma unroll
                    for (int it = 0; it < 4; it++) {
                        int f = it * 256 + tid, r = f >> 5, c4 = f & 31;
                        av[it] = *(const floatx4*)(xm + (size_t)(nrow0 + r) * 256 + nh * 128 + c4 * 4);
                    }
                    #pragma unroll
                    for (int it = 0; it < 9; it++) {
                        int idx = it * 256 + tid, n = idx >> 4, ch = idx & 15;
                        bv[it] = *(const intx4*)&btq[(size_t)nh * 18432 + n * 128 + ch * 8];
                    }
                }
                // MFMA from LDS
                #pragma unroll
                for (int ks = 0; ks < 4; ks++) {
                    int ko = ks * 32 + quad * 8;
                    shortx8 a0 = *(const shortx8*)&a_lds[(s * 16 + low) * 136 + ko];
                    #pragma unroll
                    for (int j = 0; j < 5; j++) {
                        if (g == 1 && j == 4) continue;
                        int nt = g * 5 + j;
                        shortx8 b = *(const shortx8*)&b_lds[(nt * 16 + low) * 136 + ko];
                        acc[j] = MFMA16(a0, b, acc[j]);
                    }
                }
            }
            // epilogue (rows exact: NM = 3125*32)
            #pragma unroll
            for (int j = 0; j < 5; j++) {
                if (g == 1 && j == 4) continue;
                int nt = g * 5 + j;
                int col = nt * 16 + low;
                #pragma unroll
                for (int r = 0; r < 4; r++) {
                    int row = row0 + s * 16 + quad * 4 + r;
                    float v = acc[j][r] + bq[col];
                    if (nt == 8) {
                        if (low < 8) skipb[(size_t)row * 8 + low] = v;
                    } else {
                        q0[(size_t)row * 128 + col] = f2bf_fast(v);
                    }
                }
            }
        }
    } else {
        // =================== director/actor ka|mv ===================
        int kbase = (bx - BLK_M) * T_K;
        floatx4 av[4];
        intx4 bv[8];
        // resolve a tile id -> sources (block-uniform)
        // preload (tile=kbase, panel=0)
        {
            int tt = kbase < NT_K ? kbase : NT_K - 1;
            const float* A; int M, row0;
            const unsigned short* BT;
            if (tt < NT_D) { A = xd; M = ND; row0 = tt * 32; BT = btd; }
            else           { A = xa; M = NA; row0 = (tt - NT_D) * 32; BT = bta; }
            #pragma unroll
            for (int it = 0; it < 4; it++) {
                int f = it * 256 + tid, r = f >> 5, c4 = f & 31;
                int rg = row0 + r; if (rg >= M) rg = M - 1;
                av[it] = *(const floatx4*)(A + (size_t)rg * 128 + c4 * 4);
            }
            #pragma unroll
            for (int it = 0; it < 8; it++) {
                int idx = it * 256 + tid, n = idx >> 4, ch = idx & 15;
                bv[it] = *(const intx4*)&BT[(size_t)n * 128 + ch * 8];
            }
        }
        for (int t = 0; t < T_K; t++) {
            int tcur = kbase + t;
            if (tcur >= NT_K) break;
            const float* A; int M, row0;
            const unsigned short* BT; const float* bias;
            unsigned short* outb;
            if (tcur < NT_D) { A = xd; M = ND; row0 = tcur * 32; BT = btd; bias = bbd; outb = outd; }
            else             { A = xa; M = NA; row0 = (tcur - NT_D) * 32; BT = bta; bias = bba; outb = outa; }

            #pragma unroll
            for (int pnl = 0; pnl < 2; pnl++) {
                __syncthreads();
                if (pnl == 0) {
                    #pragma unroll
                    for (int it = 0; it < 4; it++) {
                        int f = it * 256 + tid, r = f >> 5, c4 = f & 31;
                        unsigned long long d =
                            ((unsigned long long)pkbf2(av[it][2], av[it][3]) << 32) |
                            pkbf2(av[it][0], av[it][1]);
                        *(unsigned long long*)&a_lds[r * 136 + c4 * 4] = d;
                    }
                }
                #pragma unroll
                for (int it = 0; it < 8; it++) {
                    int idx = it * 256 + tid, n = idx >> 4, ch = idx & 15;
                    *(intx4*)&b_lds[n * 136 + ch * 8] = bv[it];
                }
                __syncthreads();
                // issue next loads
                if (pnl == 0) {
                    #pragma unroll
                    for (int it = 0; it < 8; it++) {
                        int idx = it * 256 + tid, n = idx >> 4, ch = idx & 15;
                        bv[it] = *(const intx4*)&BT[16384 + (size_t)n * 128 + ch * 8];
                    }
                } else {
                    int tn = (tcur + 1 < NT_K) ? tcur + 1 : NT_K - 1;
                    const float* An; int Mn, nrow0;
                    const unsigned short* BTn;
                    if (tn < NT_D) { An = xd; Mn = ND; nrow0 = tn * 32; BTn = btd; }
                    else           { An = xa; Mn = NA; nrow0 = (tn - NT_D) * 32; BTn = bta; }
                    #pragma unroll
                    for (int it = 0; it < 4; it++) {
                        int f = it * 256 + tid, r = f >> 5, c4 = f & 31;
                        int rg = nrow0 + r; if (rg >= Mn) rg = Mn - 1;
                        av[it] = *(const floatx4*)(An + (size_t)rg * 128 + c4 * 4);
                    }
                    #pragma unroll
                    for (int it = 0; it < 8; it++) {
                        int idx = it * 256 + tid, n = idx >> 4, ch = idx & 15;
                        bv[it] = *(const intx4*)&BTn[(size_t)n * 128 + ch * 8];
                    }
                }
                // MFMA
                floatx4 acc[4] = {};
                #pragma unroll
                for (int ks = 0; ks < 4; ks++) {
                    int ko = ks * 32 + quad * 8;
                    shortx8 a0 = *(const shortx8*)&a_lds[(s * 16 + low) * 136 + ko];
                    #pragma unroll
                    for (int j = 0; j < 4; j++) {
                        int nt = g * 4 + j;
                        shortx8 b = *(const shortx8*)&b_lds[(nt * 16 + low) * 136 + ko];
                        acc[j] = MFMA16(a0, b, acc[j]);
                    }
                }
                // epilogue
                #pragma unroll
                for (int j = 0; j < 4; j++) {
                    int nt = g * 4 + j;
                    int col = pnl * 128 + nt * 16 + low;
                    #pragma unroll
                    for (int r = 0; r < 4; r++) {
                        int row = row0 + s * 16 + quad * 4 + r;
                        if (row < M)
                            outb[(size_t)row * 256 + col] = f2bf_fast(acc[j][r] + bias[pnl * 128 + nt * 16 + low]);
                    }
                }
            }
        }
    }
}

// ---------------------------------------------------------------------------
// Aggregation: 16 lanes/node, 4 nodes/wave, 1-deep edge prefetch.
// ---------------------------------------------------------------------------
__global__ __launch_bounds__(256) void agg_kernel(
    const unsigned short* __restrict__ q0,
    const char* __restrict__ kamv0,      // = ws + OFF_KAMV_D
    const int* __restrict__ counts, const int* __restrict__ slots,
    const float* __restrict__ skipb,
    const float* __restrict__ WaLs, const float* __restrict__ bfin,
    float* __restrict__ out)
{
    __shared__ float wals[1032];   // [c][j*16+L] transposed-interleaved + bfin
    for (int i = threadIdx.x; i < 1024; i += 256) {
        int c = i >> 7, rem = i & 127, j = rem >> 4, L = rem & 15;
        wals[i] = WaLs[(L * 8 + j) * 8 + c];
    }
    if (threadIdx.x < 8) wals[1024 + threadIdx.x] = bfin[threadIdx.x];
    __syncthreads();

    int lane = threadIdx.x & 63;
    int grp = lane >> 4;
    int L   = lane & 15;
    int n = blockIdx.x * 16 + (threadIdx.x >> 6) * 4 + grp;

    intx4 qv = *(const intx4*)(q0 + (size_t)n * 128 + L * 8);
    float qf[8];
    #pragma unroll
    for (int d = 0; d < 4; d++) {
        unsigned int u = (unsigned int)qv[d];
        qf[2 * d]     = __uint_as_float(u << 16);
        qf[2 * d + 1] = __uint_as_float(u & 0xffff0000u);
    }

    int cnt = counts[n];
    cnt = cnt < 0 ? 0 : (cnt > CAP ? CAP : cnt);
    int s0 = slots[(size_t)n * CAP + L];

    float acc[8] = {0, 0, 0, 0, 0, 0, 0, 0};
    float den = 0.0f;
    if (cnt > 0) {
        int off0 = __shfl(s0, lane & 48);
        const char* p = kamv0 + off0;
        intx4 ku = *(const intx4*)(p + L * 16);
        intx4 mu = *(const intx4*)(p + 256 + L * 16);
        for (int i = 0; i < cnt; i++) {
            int inext = (i + 1 < cnt) ? i + 1 : i;
            int offn = __shfl(s0, (lane & 48) + (inext & 15));
            if (__builtin_expect(inext >= 16, 0)) offn = slots[(size_t)n * CAP + inext];
            const char* pn = kamv0 + offn;
            intx4 kun = *(const intx4*)(pn + L * 16);
            intx4 mun = *(const intx4*)(pn + 256 + L * 16);

            float ph = 0.0f;
            #pragma unroll
            for (int d = 0; d < 4; d++) {
                unsigned int u = (unsigned int)ku[d];
                ph += qf[2 * d]     * __uint_as_float(u << 16);
                ph += qf[2 * d + 1] * __uint_as_float(u & 0xffff0000u);
            }
            float pf = ph + __shfl_xor(ph, 1);
            float wgt = __expf(fminf(pf, 60.0f));
            den += wgt;
            #pragma unroll
            for (int d = 0; d < 4; d++) {
                unsigned int u = (unsigned int)mu[d];
                acc[2 * d]     += wgt * __uint_as_float(u << 16);
                acc[2 * d + 1] += wgt * __uint_as_float(u & 0xffff0000u);
            }
            ku = kun; mu = mun;
        }
    }
    float inv = 1.0f / fmaxf(den, 1e-16f);

    float part[8] = {0, 0, 0, 0, 0, 0, 0, 0};
    #pragma unroll
    for (int j = 0; j < 8; j++) {
        float u = gelu_exact(acc[j] * inv);
        #pragma unroll
        for (int c = 0; c < 8; c++)
            part[c] += u * wals[c * 128 + j * 16 + L];
    }

    bool b0 = lane & 1, b1 = lane & 2, b2 = lane & 4;
    float t1[4], t2[2], t3;
    #pragma unroll
    for (int k = 0; k < 4; k++) {
        float send = b0 ? part[k] : part[4 + k];
        float got  = __shfl_xor(send, 1);
        t1[k] = (b0 ? part[4 + k] : part[k]) + got;
    }
    #pragma unroll
    for (int k = 0; k < 2; k++) {
        float send = b1 ? t1[k] : t1[2 + k];
        float got  = __shfl_xor(send, 2);
        t2[k] = (b1 ? t1[2 + k] : t1[k]) + got;
    }
    {
        float send = b2 ? t2[0] : t2[1];
        float got  = __shfl_xor(send, 4);
        t3 = (b2 ? t2[1] : t2[0]) + got;
    }
    t3 += __shfl_xor(t3, 8);
    if (L < 8) {
        int c = 4 * (L & 1) + 2 * ((L >> 1) & 1) + ((L >> 2) & 1);
        out[(size_t)n * 8 + c] = t3 + skipb[(size_t)n * 8 + c] + wals[1024 + c];
    }
}

// ---------------------------------------------------------------------------
// Host launch — 4 dispatches
// ---------------------------------------------------------------------------
extern "C" void kernel_launch(void* const* d_in, const int* in_sizes, int n_in,
                              void* d_out, int out_size, void* d_ws, size_t ws_size,
                              hipStream_t stream) {
    (void)in_sizes; (void)n_in; (void)out_size; (void)ws_size;
    const float* x_movie    = (const float*)d_in[0];
    const float* x_director = (const float*)d_in[1];
    const float* x_actor    = (const float*)d_in[2];
    const int* src_dm = (const int*)d_in[3];
    const int* dst_dm = (const int*)d_in[4];
    const int* src_am = (const int*)d_in[5];
    const int* dst_am = (const int*)d_in[6];
    const float* Wpre_m = (const float*)d_in[11];
    const float* Wpre_d = (const float*)d_in[12];
    const float* Wpre_a = (const float*)d_in[13];
    const float* bpre   = (const float*)d_in[14];
    const float* Wk     = (const float*)d_in[15];
    const float* bk     = (const float*)d_in[16];
    const float* Wq     = (const float*)d_in[17];
    const float* bq     = (const float*)d_in[18];
    const float* Wv     = (const float*)d_in[19];
    const float* bv     = (const float*)d_in[20];
    const float* a_rel  = (const float*)d_in[21];
    const float* m_rel  = (const float*)d_in[22];
    const float* p_rel  = (const float*)d_in[23];
    const float* skip   = (const float*)d_in[24];
    const float* Wa     = (const float*)d_in[25];
    const float* ba     = (const float*)d_in[26];
    const float* Wlin   = (const float*)d_in[27];
    const float* blin   = (const float*)d_in[28];

    char* ws = (char*)d_ws;
    float* out = (float*)d_out;

    precompA<<<(83464 + NM + 255) / 256, 256, 0, stream>>>(
        Wk, bk, Wv, bv, Wa, ba, Wlin, blin,
        a_rel, m_rel, p_rel, skip, bpre, Wq, ws);

    prep_scat<<<2344 + 403, 256, 0, stream>>>(
        src_dm, dst_dm, src_am, dst_am,
        Wpre_m, Wpre_d, Wpre_a, bpre, bq, Wlin, skip, ws);

    gemm_all<<<BLK_M + BLK_K, 256, 0, stream>>>(
        x_movie, x_director, x_actor,
        (const unsigned short*)(ws + OFF_BT_Q),
        (const unsigned short*)(ws + OFF_BT_KAMV_D),
        (const unsigned short*)(ws + OFF_BT_KAMV_A),
        (const float*)(ws + OFF_BQ),
        (const float*)(ws + OFF_B_KAMV_D), (const float*)(ws + OFF_B_KAMV_A),
        (unsigned short*)(ws + OFF_Q0), (float*)(ws + OFF_SKIPB),
        (unsigned short*)(ws + OFF_KAMV_D), (unsigned short*)(ws + OFF_KAMV_A));

    agg_kernel<<<NM / 16, 256, 0, stream>>>(
        (const unsigned short*)(ws + OFF_Q0),
        (const char*)(ws + OFF_KAMV_D),
        (const int*)(ws + OFF_COUNTS), (const int*)(ws + OFF_SLOTS),
        (const float*)(ws + OFF_SKIPB),
        (const float*)(ws + OFF_WALS), (const float*)(ws + OFF_BFIN), out);
}